// Round 2
// baseline (1048.292 us; speedup 1.0000x reference)
//
#include <hip/hip_runtime.h>
#include <cstdint>

#define NTOK 8192
#define DIM  1024
#define HID  2048
#define MATE (2048*1024)

typedef __attribute__((ext_vector_type(8))) short short8;
typedef __attribute__((ext_vector_type(4))) float f32x4;

typedef unsigned int __attribute__((address_space(1)))* gptr_t;
typedef unsigned int __attribute__((address_space(3)))* lptr_t;

__device__ __forceinline__ unsigned short f2bf(float f) {
  unsigned u = __builtin_bit_cast(unsigned, f);
  u += 0x7fffu + ((u >> 16) & 1u);
  return (unsigned short)(u >> 16);
}

__device__ __forceinline__ void gl_lds16(const void* g, void* l) {
  __builtin_amdgcn_global_load_lds((gptr_t)g, (lptr_t)l, 16, 0, 0);
}

// ---------------- gating ----------------
__global__ __launch_bounds__(256) void k_gate(const float* __restrict__ x,
    const float* __restrict__ gw, int* __restrict__ topi, float* __restrict__ topw,
    int* __restrict__ counts)
{
  int lane = threadIdx.x & 63;
  int t = blockIdx.x * 4 + (threadIdx.x >> 6);
  const float* xr = x + (size_t)t * DIM;
  float a0=0,a1=0,a2=0,a3=0,a4=0,a5=0,a6=0,a7=0;
  for (int i = 0; i < 16; ++i) {
    int idx = lane + (i << 6);
    float xv = xr[idx];
    float4 g0 = *reinterpret_cast<const float4*>(gw + idx*8);
    float4 g1 = *reinterpret_cast<const float4*>(gw + idx*8 + 4);
    a0 += xv*g0.x; a1 += xv*g0.y; a2 += xv*g0.z; a3 += xv*g0.w;
    a4 += xv*g1.x; a5 += xv*g1.y; a6 += xv*g1.z; a7 += xv*g1.w;
  }
  float acc[8] = {a0,a1,a2,a3,a4,a5,a6,a7};
  #pragma unroll
  for (int e = 0; e < 8; ++e)
    for (int off = 32; off >= 1; off >>= 1)
      acc[e] += __shfl_xor(acc[e], off, 64);
  if (lane == 0) {
    int i0 = 0; float v0 = acc[0];
    #pragma unroll
    for (int e = 1; e < 8; ++e) if (acc[e] > v0) { v0 = acc[e]; i0 = e; }
    int i1 = -1; float v1 = -3.4e38f;
    #pragma unroll
    for (int e = 0; e < 8; ++e) if (e != i0 && acc[e] > v1) { v1 = acc[e]; i1 = e; }
    float p0 = 1.f / (1.f + __expf(v1 - v0));
    topi[2*t] = i0; topi[2*t+1] = i1;
    topw[2*t] = p0; topw[2*t+1] = 1.f - p0;
    atomicAdd(&counts[i0], 1); atomicAdd(&counts[i1], 1);
  }
}

__global__ void k_scan(const int* __restrict__ counts, int* __restrict__ offs,
                       int* __restrict__ fill)
{
  if (threadIdx.x == 0) {
    int s = 0;
    for (int e = 0; e < 8; ++e) { offs[e] = s; fill[e] = s; s += counts[e]; }
    offs[8] = s;
  }
}

__global__ __launch_bounds__(256) void k_scatter(const int* __restrict__ topi,
    const float* __restrict__ topw, int* __restrict__ fill,
    int* __restrict__ entry, float* __restrict__ wgt)
{
  int t = blockIdx.x * 256 + threadIdx.x;
  #pragma unroll
  for (int k = 0; k < 2; ++k) {
    int e = topi[2*t + k];
    int pos = atomicAdd(&fill[e], 1);
    entry[pos] = t;
    wgt[pos] = topw[2*t + k];
  }
}

// ---------------- x -> bf16 ----------------
__global__ __launch_bounds__(256) void k_castx(const float* __restrict__ x,
    unsigned short* __restrict__ xb)
{
  int i = blockIdx.x * 256 + threadIdx.x;
  float4 v = reinterpret_cast<const float4*>(x)[i];
  ushort4 o; o.x = f2bf(v.x); o.y = f2bf(v.y); o.z = f2bf(v.z); o.w = f2bf(v.w);
  reinterpret_cast<ushort4*>(xb)[i] = o;
}

// ------------- weight transpose+cast: src f32 [R][C] -> dst bf16 [C][R] -------------
__global__ __launch_bounds__(256) void k_tr(const float* __restrict__ ew1,
    const float* __restrict__ ew2, const float* __restrict__ ew3,
    const float* __restrict__ sw1, const float* __restrict__ sw2,
    const float* __restrict__ sw3, unsigned short* __restrict__ wt)
{
  int z = blockIdx.z;
  const float* src; int R, C;
  if (z < 8)        { src = ew1 + (size_t)z * MATE;      R = 1024; C = 2048; }
  else if (z < 16)  { src = ew2 + (size_t)(z-8) * MATE;  R = 1024; C = 2048; }
  else if (z < 24)  { src = ew3 + (size_t)(z-16) * MATE; R = 2048; C = 1024; }
  else if (z == 24) { src = sw1; R = 1024; C = 2048; }
  else if (z == 25) { src = sw2; R = 1024; C = 2048; }
  else              { src = sw3; R = 2048; C = 1024; }
  unsigned short* dst = wt + (size_t)z * MATE;
  int cb = blockIdx.x * 64, rb = blockIdx.y * 64;
  if (cb >= C || rb >= R) return;
  __shared__ float tile[64][65];
  int tid = threadIdx.x;
  int lr = tid >> 4, lc = (tid & 15) * 4;
  #pragma unroll
  for (int i = 0; i < 4; ++i) {
    int r = lr + i*16;
    float4 v = *reinterpret_cast<const float4*>(src + (size_t)(rb + r) * C + cb + lc);
    tile[r][lc] = v.x; tile[r][lc+1] = v.y; tile[r][lc+2] = v.z; tile[r][lc+3] = v.w;
  }
  __syncthreads();
  #pragma unroll
  for (int i = 0; i < 4; ++i) {
    int c = lr + i*16;
    int r = lc;
    ushort4 o;
    o.x = f2bf(tile[r][c]);   o.y = f2bf(tile[r+1][c]);
    o.z = f2bf(tile[r+2][c]); o.w = f2bf(tile[r+3][c]);
    *reinterpret_cast<ushort4*>(dst + (size_t)(cb + c) * R + rb + r) = o;
  }
}

// ------------- up-proj (dual-B) + SwiGLU -> act bf16, 2-phase dbuf -------------
__global__ __launch_bounds__(256) void k_up(const unsigned short* __restrict__ xb,
    const unsigned short* __restrict__ wt, const int* __restrict__ offs,
    const int* __restrict__ entry, unsigned short* __restrict__ act)
{
  __shared__ __align__(16) unsigned short Al[2][128*32];
  __shared__ __align__(16) unsigned short B1l[2][128*32];
  __shared__ __align__(16) unsigned short B2l[2][128*32];
  int tid = threadIdx.x, lane = tid & 63, w = tid >> 6;
  int nb = blockIdx.x, yb = blockIdx.y;
  int mbase, mend, arow0; const unsigned short *w1, *w2; bool is_sh;
  if (yb < 512) {
    int seg = yb >> 6, mb = yb & 63;
    int s0 = offs[seg], s1 = offs[seg+1];
    mbase = s0 + mb*128;
    if (mbase >= s1) return;
    mend = s1; arow0 = mbase;
    w1 = wt + (size_t)seg * MATE; w2 = wt + (size_t)(8+seg) * MATE; is_sh = false;
  } else {
    int mb = yb - 512; mbase = mb*128; mend = NTOK; arow0 = 16384 + mbase;
    w1 = wt + (size_t)24 * MATE; w2 = wt + (size_t)25 * MATE; is_sh = true;
  }
  int r0 = w*32 + (lane >> 2), r1 = r0 + 16;
  int m0 = mbase + r0, m1 = mbase + r1;
  int tokA0 = is_sh ? m0 : ((m0 < mend) ? entry[m0] : 0);
  int tokA1 = is_sh ? m1 : ((m1 < mend) ? entry[m1] : 0);
  int g4 = (lane & 3) * 8;
  const unsigned short* ga0 = xb + (size_t)tokA0 * DIM + g4;
  const unsigned short* ga1 = xb + (size_t)tokA1 * DIM + g4;
  int n0 = nb * 128;
  const unsigned short* gb1a = w1 + (size_t)(n0 + r0) * DIM + g4;
  const unsigned short* gb1b = w1 + (size_t)(n0 + r1) * DIM + g4;
  const unsigned short* gb2a = w2 + (size_t)(n0 + r0) * DIM + g4;
  const unsigned short* gb2b = w2 + (size_t)(n0 + r1) * DIM + g4;
  unsigned loff0 = (unsigned)__builtin_amdgcn_readfirstlane(w * 2048);
  unsigned loff1 = loff0 + 1024;
  int r16 = lane & 15, kg = lane >> 4, wr = w >> 1, wc = w & 1;
  int aoff[4], boff[4];
  #pragma unroll
  for (int m = 0; m < 4; ++m) aoff[m] = ((wr*64 + m*16 + r16)*32 + kg*8) * 2;
  #pragma unroll
  for (int n = 0; n < 4; ++n) boff[n] = ((wc*64 + n*16 + r16)*32 + kg*8) * 2;
  const f32x4 fz = {0.f, 0.f, 0.f, 0.f};
  f32x4 acc1[4][4], acc2[4][4];
  #pragma unroll
  for (int m = 0; m < 4; ++m)
    #pragma unroll
    for (int n = 0; n < 4; ++n) { acc1[m][n] = fz; acc2[m][n] = fz; }

  // prologue stage into buf 0
  gl_lds16(ga0,  (char*)&Al[0][0]  + loff0);
  gl_lds16(ga1,  (char*)&Al[0][0]  + loff1);
  gl_lds16(gb1a, (char*)&B1l[0][0] + loff0);
  gl_lds16(gb1b, (char*)&B1l[0][0] + loff1);
  gl_lds16(gb2a, (char*)&B2l[0][0] + loff0);
  gl_lds16(gb2b, (char*)&B2l[0][0] + loff1);
  __syncthreads();

  #pragma unroll 2
  for (int t = 0; t < 32; ++t) {
    int cur = t & 1;
    if (t < 31) {
      int kn = (t + 1) * 32;
      char* ab  = (char*)&Al[cur ^ 1][0];
      char* b1b = (char*)&B1l[cur ^ 1][0];
      char* b2b = (char*)&B2l[cur ^ 1][0];
      gl_lds16(ga0 + kn,  ab  + loff0);
      gl_lds16(ga1 + kn,  ab  + loff1);
      gl_lds16(gb1a + kn, b1b + loff0);
      gl_lds16(gb1b + kn, b1b + loff1);
      gl_lds16(gb2a + kn, b2b + loff0);
      gl_lds16(gb2b + kn, b2b + loff1);
    }
    const char* Ab  = (const char*)&Al[cur][0];
    const char* B1b = (const char*)&B1l[cur][0];
    const char* B2b = (const char*)&B2l[cur][0];
    short8 a[4], b1v[4], b2v[4];
    #pragma unroll
    for (int m = 0; m < 4; ++m) a[m] = *(const short8*)(Ab + aoff[m]);
    #pragma unroll
    for (int n = 0; n < 4; ++n) {
      b1v[n] = *(const short8*)(B1b + boff[n]);
      b2v[n] = *(const short8*)(B2b + boff[n]);
    }
    #pragma unroll
    for (int m = 0; m < 4; ++m)
      #pragma unroll
      for (int n = 0; n < 4; ++n) {
        acc1[m][n] = __builtin_amdgcn_mfma_f32_16x16x32_bf16(a[m], b1v[n], acc1[m][n], 0, 0, 0);
        acc2[m][n] = __builtin_amdgcn_mfma_f32_16x16x32_bf16(a[m], b2v[n], acc2[m][n], 0, 0, 0);
      }
    __syncthreads();
  }
  #pragma unroll
  for (int m = 0; m < 4; ++m) {
    int trb = wr*64 + m*16 + kg*4;
    #pragma unroll
    for (int n = 0; n < 4; ++n) {
      int col = n0 + wc*64 + n*16 + r16;
      #pragma unroll
      for (int j = 0; j < 4; ++j) {
        int tr = trb + j;
        if (mbase + tr < mend) {
          float h1 = acc1[m][n][j], h2 = acc2[m][n][j];
          float sv = h1 / (1.f + __expf(-h1)) * h2;
          act[(size_t)(arow0 + tr) * HID + col] = f2bf(sv);
        }
      }
    }
  }
}

// ------------- down-proj: act @ w3^T -> out, 2-phase dbuf -------------
template<bool SH>
__global__ __launch_bounds__(256) void k_down(const unsigned short* __restrict__ act,
    const unsigned short* __restrict__ wt, const int* __restrict__ offs,
    const int* __restrict__ entry, const float* __restrict__ wgt,
    float* __restrict__ out)
{
  __shared__ __align__(16) unsigned short Al[2][128*32];
  __shared__ __align__(16) unsigned short Bl[2][128*32];
  int tid = threadIdx.x, lane = tid & 63, w = tid >> 6;
  int nb = blockIdx.x, yb = blockIdx.y;
  int mbase, mend, arow0; const unsigned short* w3;
  if (SH) {
    mbase = yb*128; mend = NTOK; arow0 = 16384 + mbase;
    w3 = wt + (size_t)26 * MATE;
  } else {
    int seg = yb >> 6, mb = yb & 63;
    int s0 = offs[seg], s1 = offs[seg+1];
    mbase = s0 + mb*128;
    if (mbase >= s1) return;
    mend = s1; arow0 = mbase;
    w3 = wt + (size_t)(16+seg) * MATE;
  }
  int r0 = w*32 + (lane >> 2), r1 = r0 + 16;
  int g4 = (lane & 3) * 8;
  const unsigned short* ga0 = act + (size_t)(arow0 + r0) * HID + g4;
  const unsigned short* ga1 = act + (size_t)(arow0 + r1) * HID + g4;
  int n0 = nb * 128;
  const unsigned short* gb0 = w3 + (size_t)(n0 + r0) * HID + g4;
  const unsigned short* gb1 = w3 + (size_t)(n0 + r1) * HID + g4;
  unsigned loff0 = (unsigned)__builtin_amdgcn_readfirstlane(w * 2048);
  unsigned loff1 = loff0 + 1024;
  int r16 = lane & 15, kg = lane >> 4, wr = w >> 1, wc = w & 1;
  int aoff[4], boff[4];
  #pragma unroll
  for (int m = 0; m < 4; ++m) aoff[m] = ((wr*64 + m*16 + r16)*32 + kg*8) * 2;
  #pragma unroll
  for (int n = 0; n < 4; ++n) boff[n] = ((wc*64 + n*16 + r16)*32 + kg*8) * 2;
  const f32x4 fz = {0.f, 0.f, 0.f, 0.f};
  f32x4 acc[4][4];
  #pragma unroll
  for (int m = 0; m < 4; ++m)
    #pragma unroll
    for (int n = 0; n < 4; ++n) acc[m][n] = fz;

  gl_lds16(ga0, (char*)&Al[0][0] + loff0);
  gl_lds16(ga1, (char*)&Al[0][0] + loff1);
  gl_lds16(gb0, (char*)&Bl[0][0] + loff0);
  gl_lds16(gb1, (char*)&Bl[0][0] + loff1);
  __syncthreads();

  #pragma unroll 2
  for (int t = 0; t < 64; ++t) {
    int cur = t & 1;
    if (t < 63) {
      int kn = (t + 1) * 32;
      char* ab = (char*)&Al[cur ^ 1][0];
      char* bb = (char*)&Bl[cur ^ 1][0];
      gl_lds16(ga0 + kn, ab + loff0);
      gl_lds16(ga1 + kn, ab + loff1);
      gl_lds16(gb0 + kn, bb + loff0);
      gl_lds16(gb1 + kn, bb + loff1);
    }
    const char* Ab = (const char*)&Al[cur][0];
    const char* Bb = (const char*)&Bl[cur][0];
    short8 a[4], b[4];
    #pragma unroll
    for (int m = 0; m < 4; ++m) a[m] = *(const short8*)(Ab + aoff[m]);
    #pragma unroll
    for (int n = 0; n < 4; ++n) b[n] = *(const short8*)(Bb + boff[n]);
    #pragma unroll
    for (int m = 0; m < 4; ++m)
      #pragma unroll
      for (int n = 0; n < 4; ++n)
        acc[m][n] = __builtin_amdgcn_mfma_f32_16x16x32_bf16(a[m], b[n], acc[m][n], 0, 0, 0);
    __syncthreads();
  }
  #pragma unroll
  for (int m = 0; m < 4; ++m) {
    int trb = wr*64 + m*16 + kg*4;
    #pragma unroll
    for (int n = 0; n < 4; ++n) {
      int col = n0 + wc*64 + n*16 + r16;
      #pragma unroll
      for (int j = 0; j < 4; ++j) {
        int tr = trb + j;
        if (mbase + tr < mend) {
          float val = acc[m][n][j];
          if (SH) {
            out[(size_t)(mbase + tr) * DIM + col] = val;
          } else {
            int tok = entry[arow0 + tr];
            float gv = wgt[arow0 + tr];
            atomicAdd(&out[(size_t)tok * DIM + col], val * gv);
          }
        }
      }
    }
  }
}

extern "C" void kernel_launch(void* const* d_in, const int* in_sizes, int n_in,
                              void* d_out, int out_size, void* d_ws, size_t ws_size,
                              hipStream_t stream)
{
  const float* x   = (const float*)d_in[0];
  const float* gw  = (const float*)d_in[1];
  const float* ew1 = (const float*)d_in[2];
  const float* ew2 = (const float*)d_in[3];
  const float* ew3 = (const float*)d_in[4];
  const float* sw1 = (const float*)d_in[5];
  const float* sw2 = (const float*)d_in[6];
  const float* sw3 = (const float*)d_in[7];
  float* out = (float*)d_out;
  char* ws = (char*)d_ws;

  int*   counts = (int*)ws;
  int*   offs   = counts + 8;
  int*   fill   = offs + 9;
  int*   topi   = fill + 8;
  float* topw   = (float*)(topi + 2*NTOK);
  int*   entry  = (int*)(topw + 2*NTOK);
  float* wgt    = (float*)(entry + 2*NTOK);
  unsigned short* xb  = (unsigned short*)(ws + (1u<<20));
  unsigned short* act = (unsigned short*)(ws + (1u<<20) + (16u<<20));
  unsigned short* wt  = (unsigned short*)(ws + (1u<<20) + (16u<<20) + (96u<<20));

  hipMemsetAsync(counts, 0, 8*sizeof(int), stream);
  k_gate<<<NTOK/4, 256, 0, stream>>>(x, gw, topi, topw, counts);
  k_scan<<<1, 64, 0, stream>>>(counts, offs, fill);
  k_scatter<<<NTOK/256, 256, 0, stream>>>(topi, topw, fill, entry, wgt);
  k_castx<<<(NTOK*DIM/4)/256, 256, 0, stream>>>(x, xb);
  k_tr<<<dim3(32, 32, 27), 256, 0, stream>>>(ew1, ew2, ew3, sw1, sw2, sw3, wt);
  k_up<<<dim3(16, 576), 256, 0, stream>>>(xb, wt, offs, entry, act);
  k_down<true><<<dim3(8, 64), 256, 0, stream>>>(act, wt, offs, entry, wgt, out);
  k_down<false><<<dim3(8, 512), 256, 0, stream>>>(act, wt, offs, entry, wgt, out);
}

// Round 3
// 1032.976 us; speedup vs baseline: 1.0148x; 1.0148x over previous
//
#include <hip/hip_runtime.h>
#include <cstdint>

#define NTOK 8192
#define DIM  1024
#define HID  2048
#define MATE (2048*1024)

typedef __attribute__((ext_vector_type(8))) short short8;
typedef __attribute__((ext_vector_type(4))) float f32x4;

typedef unsigned int __attribute__((address_space(1)))* gptr_t;
typedef unsigned int __attribute__((address_space(3)))* lptr_t;

__device__ __forceinline__ unsigned short f2bf(float f) {
  unsigned u = __builtin_bit_cast(unsigned, f);
  u += 0x7fffu + ((u >> 16) & 1u);
  return (unsigned short)(u >> 16);
}

__device__ __forceinline__ void gl_lds16(const void* g, void* l) {
  __builtin_amdgcn_global_load_lds((gptr_t)g, (lptr_t)l, 16, 0, 0);
}

// ---------------- gating ----------------
__global__ __launch_bounds__(256) void k_gate(const float* __restrict__ x,
    const float* __restrict__ gw, int* __restrict__ topi, float* __restrict__ topw,
    int* __restrict__ counts)
{
  int lane = threadIdx.x & 63;
  int t = blockIdx.x * 4 + (threadIdx.x >> 6);
  const float* xr = x + (size_t)t * DIM;
  float a0=0,a1=0,a2=0,a3=0,a4=0,a5=0,a6=0,a7=0;
  for (int i = 0; i < 16; ++i) {
    int idx = lane + (i << 6);
    float xv = xr[idx];
    float4 g0 = *reinterpret_cast<const float4*>(gw + idx*8);
    float4 g1 = *reinterpret_cast<const float4*>(gw + idx*8 + 4);
    a0 += xv*g0.x; a1 += xv*g0.y; a2 += xv*g0.z; a3 += xv*g0.w;
    a4 += xv*g1.x; a5 += xv*g1.y; a6 += xv*g1.z; a7 += xv*g1.w;
  }
  float acc[8] = {a0,a1,a2,a3,a4,a5,a6,a7};
  #pragma unroll
  for (int e = 0; e < 8; ++e)
    for (int off = 32; off >= 1; off >>= 1)
      acc[e] += __shfl_xor(acc[e], off, 64);
  if (lane == 0) {
    int i0 = 0; float v0 = acc[0];
    #pragma unroll
    for (int e = 1; e < 8; ++e) if (acc[e] > v0) { v0 = acc[e]; i0 = e; }
    int i1 = -1; float v1 = -3.4e38f;
    #pragma unroll
    for (int e = 0; e < 8; ++e) if (e != i0 && acc[e] > v1) { v1 = acc[e]; i1 = e; }
    float p0 = 1.f / (1.f + __expf(v1 - v0));
    topi[2*t] = i0; topi[2*t+1] = i1;
    topw[2*t] = p0; topw[2*t+1] = 1.f - p0;
    atomicAdd(&counts[i0], 1); atomicAdd(&counts[i1], 1);
  }
}

__global__ void k_scan(const int* __restrict__ counts, int* __restrict__ offs,
                       int* __restrict__ fill)
{
  if (threadIdx.x == 0) {
    int s = 0;
    for (int e = 0; e < 8; ++e) { offs[e] = s; fill[e] = s; s += counts[e]; }
    offs[8] = s;
  }
}

__global__ __launch_bounds__(256) void k_scatter(const int* __restrict__ topi,
    const float* __restrict__ topw, int* __restrict__ fill,
    int* __restrict__ entry, float* __restrict__ wgt)
{
  int t = blockIdx.x * 256 + threadIdx.x;
  #pragma unroll
  for (int k = 0; k < 2; ++k) {
    int e = topi[2*t + k];
    int pos = atomicAdd(&fill[e], 1);
    entry[pos] = t;
    wgt[pos] = topw[2*t + k];
  }
}

// ---------------- x -> bf16 ----------------
__global__ __launch_bounds__(256) void k_castx(const float* __restrict__ x,
    unsigned short* __restrict__ xb)
{
  int i = blockIdx.x * 256 + threadIdx.x;
  float4 v = reinterpret_cast<const float4*>(x)[i];
  ushort4 o; o.x = f2bf(v.x); o.y = f2bf(v.y); o.z = f2bf(v.z); o.w = f2bf(v.w);
  reinterpret_cast<ushort4*>(xb)[i] = o;
}

// ------------- weight transpose+cast: src f32 [R][C] -> dst bf16 [C][R] -------------
__global__ __launch_bounds__(256) void k_tr(const float* __restrict__ ew1,
    const float* __restrict__ ew2, const float* __restrict__ ew3,
    const float* __restrict__ sw1, const float* __restrict__ sw2,
    const float* __restrict__ sw3, unsigned short* __restrict__ wt)
{
  int z = blockIdx.z;
  const float* src; int R, C;
  if (z < 8)        { src = ew1 + (size_t)z * MATE;      R = 1024; C = 2048; }
  else if (z < 16)  { src = ew2 + (size_t)(z-8) * MATE;  R = 1024; C = 2048; }
  else if (z < 24)  { src = ew3 + (size_t)(z-16) * MATE; R = 2048; C = 1024; }
  else if (z == 24) { src = sw1; R = 1024; C = 2048; }
  else if (z == 25) { src = sw2; R = 1024; C = 2048; }
  else              { src = sw3; R = 2048; C = 1024; }
  unsigned short* dst = wt + (size_t)z * MATE;
  int cb = blockIdx.x * 64, rb = blockIdx.y * 64;
  if (cb >= C || rb >= R) return;
  __shared__ float tile[64][65];
  int tid = threadIdx.x;
  int lr = tid >> 4, lc = (tid & 15) * 4;
  #pragma unroll
  for (int i = 0; i < 4; ++i) {
    int r = lr + i*16;
    float4 v = *reinterpret_cast<const float4*>(src + (size_t)(rb + r) * C + cb + lc);
    tile[r][lc] = v.x; tile[r][lc+1] = v.y; tile[r][lc+2] = v.z; tile[r][lc+3] = v.w;
  }
  __syncthreads();
  #pragma unroll
  for (int i = 0; i < 4; ++i) {
    int c = lr + i*16;
    int r = lc;
    ushort4 o;
    o.x = f2bf(tile[r][c]);   o.y = f2bf(tile[r+1][c]);
    o.z = f2bf(tile[r+2][c]); o.w = f2bf(tile[r+3][c]);
    *reinterpret_cast<ushort4*>(dst + (size_t)(cb + c) * R + rb + r) = o;
  }
}

// ------------- up-proj (dual-B) + SwiGLU -> act bf16, 2-phase dbuf, swizzled LDS -------------
// Swizzle (rule #21 both-sides): LDS[row][c] = global[row][c ^ ((row>>1)&3)],
// realized by pre-swizzling the per-lane GLOBAL chunk (LDS dest stays linear),
// and XOR-ing the same on the ds_read offsets. Pure permutation: bit-identical math.
__global__ __launch_bounds__(256) void k_up(const unsigned short* __restrict__ xb,
    const unsigned short* __restrict__ wt, const int* __restrict__ offs,
    const int* __restrict__ entry, unsigned short* __restrict__ act)
{
  __shared__ __align__(16) unsigned short Al[2][128*32];
  __shared__ __align__(16) unsigned short B1l[2][128*32];
  __shared__ __align__(16) unsigned short B2l[2][128*32];
  int tid = threadIdx.x, lane = tid & 63, w = tid >> 6;
  int nb = blockIdx.x, yb = blockIdx.y;
  int mbase, mend, arow0; const unsigned short *w1, *w2; bool is_sh;
  if (yb < 512) {
    int seg = yb >> 6, mb = yb & 63;
    int s0 = offs[seg], s1 = offs[seg+1];
    mbase = s0 + mb*128;
    if (mbase >= s1) return;
    mend = s1; arow0 = mbase;
    w1 = wt + (size_t)seg * MATE; w2 = wt + (size_t)(8+seg) * MATE; is_sh = false;
  } else {
    int mb = yb - 512; mbase = mb*128; mend = NTOK; arow0 = 16384 + mbase;
    w1 = wt + (size_t)24 * MATE; w2 = wt + (size_t)25 * MATE; is_sh = true;
  }
  int r0 = w*32 + (lane >> 2), r1 = r0 + 16;
  int m0 = mbase + r0, m1 = mbase + r1;
  int tokA0 = is_sh ? m0 : ((m0 < mend) ? entry[m0] : 0);
  int tokA1 = is_sh ? m1 : ((m1 < mend) ? entry[m1] : 0);
  // pre-swizzled global chunk: (lane&3) ^ ((row>>1)&3), (row>>1)&3 == (lane>>3)&3
  int g4 = (((lane & 3) ^ ((lane >> 3) & 3))) * 8;
  const unsigned short* ga0 = xb + (size_t)tokA0 * DIM + g4;
  const unsigned short* ga1 = xb + (size_t)tokA1 * DIM + g4;
  int n0 = nb * 128;
  const unsigned short* gb1a = w1 + (size_t)(n0 + r0) * DIM + g4;
  const unsigned short* gb1b = w1 + (size_t)(n0 + r1) * DIM + g4;
  const unsigned short* gb2a = w2 + (size_t)(n0 + r0) * DIM + g4;
  const unsigned short* gb2b = w2 + (size_t)(n0 + r1) * DIM + g4;
  unsigned loff0 = (unsigned)__builtin_amdgcn_readfirstlane(w * 2048);
  unsigned loff1 = loff0 + 1024;
  int r16 = lane & 15, kg = lane >> 4, wr = w >> 1, wc = w & 1;
  int rswz = (r16 >> 1) & 3;   // (row>>1)&3 for rows of form 16a + r16
  int aoff[4], boff[4];
  #pragma unroll
  for (int m = 0; m < 4; ++m)
    aoff[m] = ((wr*64 + m*16 + r16)*4 + (kg ^ rswz)) * 16;
  #pragma unroll
  for (int n = 0; n < 4; ++n)
    boff[n] = ((wc*64 + n*16 + r16)*4 + (kg ^ rswz)) * 16;
  const f32x4 fz = {0.f, 0.f, 0.f, 0.f};
  f32x4 acc1[4][4], acc2[4][4];
  #pragma unroll
  for (int m = 0; m < 4; ++m)
    #pragma unroll
    for (int n = 0; n < 4; ++n) { acc1[m][n] = fz; acc2[m][n] = fz; }

  // prologue stage into buf 0
  gl_lds16(ga0,  (char*)&Al[0][0]  + loff0);
  gl_lds16(ga1,  (char*)&Al[0][0]  + loff1);
  gl_lds16(gb1a, (char*)&B1l[0][0] + loff0);
  gl_lds16(gb1b, (char*)&B1l[0][0] + loff1);
  gl_lds16(gb2a, (char*)&B2l[0][0] + loff0);
  gl_lds16(gb2b, (char*)&B2l[0][0] + loff1);
  __syncthreads();

  #pragma unroll 2
  for (int t = 0; t < 32; ++t) {
    int cur = t & 1;
    if (t < 31) {
      int kn = (t + 1) * 32;
      char* ab  = (char*)&Al[cur ^ 1][0];
      char* b1b = (char*)&B1l[cur ^ 1][0];
      char* b2b = (char*)&B2l[cur ^ 1][0];
      gl_lds16(ga0 + kn,  ab  + loff0);
      gl_lds16(ga1 + kn,  ab  + loff1);
      gl_lds16(gb1a + kn, b1b + loff0);
      gl_lds16(gb1b + kn, b1b + loff1);
      gl_lds16(gb2a + kn, b2b + loff0);
      gl_lds16(gb2b + kn, b2b + loff1);
    }
    const char* Ab  = (const char*)&Al[cur][0];
    const char* B1b = (const char*)&B1l[cur][0];
    const char* B2b = (const char*)&B2l[cur][0];
    short8 a[4], b1v[4], b2v[4];
    #pragma unroll
    for (int m = 0; m < 4; ++m) a[m] = *(const short8*)(Ab + aoff[m]);
    #pragma unroll
    for (int n = 0; n < 4; ++n) {
      b1v[n] = *(const short8*)(B1b + boff[n]);
      b2v[n] = *(const short8*)(B2b + boff[n]);
    }
    #pragma unroll
    for (int m = 0; m < 4; ++m)
      #pragma unroll
      for (int n = 0; n < 4; ++n) {
        acc1[m][n] = __builtin_amdgcn_mfma_f32_16x16x32_bf16(a[m], b1v[n], acc1[m][n], 0, 0, 0);
        acc2[m][n] = __builtin_amdgcn_mfma_f32_16x16x32_bf16(a[m], b2v[n], acc2[m][n], 0, 0, 0);
      }
    __syncthreads();
  }
  #pragma unroll
  for (int m = 0; m < 4; ++m) {
    int trb = wr*64 + m*16 + kg*4;
    #pragma unroll
    for (int n = 0; n < 4; ++n) {
      int col = n0 + wc*64 + n*16 + r16;
      #pragma unroll
      for (int j = 0; j < 4; ++j) {
        int tr = trb + j;
        if (mbase + tr < mend) {
          float h1 = acc1[m][n][j], h2 = acc2[m][n][j];
          float sv = h1 / (1.f + __expf(-h1)) * h2;
          act[(size_t)(arow0 + tr) * HID + col] = f2bf(sv);
        }
      }
    }
  }
}

// ------------- down-proj: act @ w3^T -> out, 2-phase dbuf, swizzled LDS -------------
template<bool SH>
__global__ __launch_bounds__(256) void k_down(const unsigned short* __restrict__ act,
    const unsigned short* __restrict__ wt, const int* __restrict__ offs,
    const int* __restrict__ entry, const float* __restrict__ wgt,
    float* __restrict__ out)
{
  __shared__ __align__(16) unsigned short Al[2][128*32];
  __shared__ __align__(16) unsigned short Bl[2][128*32];
  int tid = threadIdx.x, lane = tid & 63, w = tid >> 6;
  int nb = blockIdx.x, yb = blockIdx.y;
  int mbase, mend, arow0; const unsigned short* w3;
  if (SH) {
    mbase = yb*128; mend = NTOK; arow0 = 16384 + mbase;
    w3 = wt + (size_t)26 * MATE;
  } else {
    int seg = yb >> 6, mb = yb & 63;
    int s0 = offs[seg], s1 = offs[seg+1];
    mbase = s0 + mb*128;
    if (mbase >= s1) return;
    mend = s1; arow0 = mbase;
    w3 = wt + (size_t)(16+seg) * MATE;
  }
  int r0 = w*32 + (lane >> 2), r1 = r0 + 16;
  int g4 = (((lane & 3) ^ ((lane >> 3) & 3))) * 8;
  const unsigned short* ga0 = act + (size_t)(arow0 + r0) * HID + g4;
  const unsigned short* ga1 = act + (size_t)(arow0 + r1) * HID + g4;
  int n0 = nb * 128;
  const unsigned short* gb0 = w3 + (size_t)(n0 + r0) * HID + g4;
  const unsigned short* gb1 = w3 + (size_t)(n0 + r1) * HID + g4;
  unsigned loff0 = (unsigned)__builtin_amdgcn_readfirstlane(w * 2048);
  unsigned loff1 = loff0 + 1024;
  int r16 = lane & 15, kg = lane >> 4, wr = w >> 1, wc = w & 1;
  int rswz = (r16 >> 1) & 3;
  int aoff[4], boff[4];
  #pragma unroll
  for (int m = 0; m < 4; ++m)
    aoff[m] = ((wr*64 + m*16 + r16)*4 + (kg ^ rswz)) * 16;
  #pragma unroll
  for (int n = 0; n < 4; ++n)
    boff[n] = ((wc*64 + n*16 + r16)*4 + (kg ^ rswz)) * 16;
  const f32x4 fz = {0.f, 0.f, 0.f, 0.f};
  f32x4 acc[4][4];
  #pragma unroll
  for (int m = 0; m < 4; ++m)
    #pragma unroll
    for (int n = 0; n < 4; ++n) acc[m][n] = fz;

  gl_lds16(ga0, (char*)&Al[0][0] + loff0);
  gl_lds16(ga1, (char*)&Al[0][0] + loff1);
  gl_lds16(gb0, (char*)&Bl[0][0] + loff0);
  gl_lds16(gb1, (char*)&Bl[0][0] + loff1);
  __syncthreads();

  #pragma unroll 2
  for (int t = 0; t < 64; ++t) {
    int cur = t & 1;
    if (t < 63) {
      int kn = (t + 1) * 32;
      char* ab = (char*)&Al[cur ^ 1][0];
      char* bb = (char*)&Bl[cur ^ 1][0];
      gl_lds16(ga0 + kn, ab + loff0);
      gl_lds16(ga1 + kn, ab + loff1);
      gl_lds16(gb0 + kn, bb + loff0);
      gl_lds16(gb1 + kn, bb + loff1);
    }
    const char* Ab = (const char*)&Al[cur][0];
    const char* Bb = (const char*)&Bl[cur][0];
    short8 a[4], b[4];
    #pragma unroll
    for (int m = 0; m < 4; ++m) a[m] = *(const short8*)(Ab + aoff[m]);
    #pragma unroll
    for (int n = 0; n < 4; ++n) b[n] = *(const short8*)(Bb + boff[n]);
    #pragma unroll
    for (int m = 0; m < 4; ++m)
      #pragma unroll
      for (int n = 0; n < 4; ++n)
        acc[m][n] = __builtin_amdgcn_mfma_f32_16x16x32_bf16(a[m], b[n], acc[m][n], 0, 0, 0);
    __syncthreads();
  }
  #pragma unroll
  for (int m = 0; m < 4; ++m) {
    int trb = wr*64 + m*16 + kg*4;
    #pragma unroll
    for (int n = 0; n < 4; ++n) {
      int col = n0 + wc*64 + n*16 + r16;
      #pragma unroll
      for (int j = 0; j < 4; ++j) {
        int tr = trb + j;
        if (mbase + tr < mend) {
          float val = acc[m][n][j];
          if (SH) {
            out[(size_t)(mbase + tr) * DIM + col] = val;
          } else {
            int tok = entry[arow0 + tr];
            float gv = wgt[arow0 + tr];
            atomicAdd(&out[(size_t)tok * DIM + col], val * gv);
          }
        }
      }
    }
  }
}

extern "C" void kernel_launch(void* const* d_in, const int* in_sizes, int n_in,
                              void* d_out, int out_size, void* d_ws, size_t ws_size,
                              hipStream_t stream)
{
  const float* x   = (const float*)d_in[0];
  const float* gw  = (const float*)d_in[1];
  const float* ew1 = (const float*)d_in[2];
  const float* ew2 = (const float*)d_in[3];
  const float* ew3 = (const float*)d_in[4];
  const float* sw1 = (const float*)d_in[5];
  const float* sw2 = (const float*)d_in[6];
  const float* sw3 = (const float*)d_in[7];
  float* out = (float*)d_out;
  char* ws = (char*)d_ws;

  int*   counts = (int*)ws;
  int*   offs   = counts + 8;
  int*   fill   = offs + 9;
  int*   topi   = fill + 8;
  float* topw   = (float*)(topi + 2*NTOK);
  int*   entry  = (int*)(topw + 2*NTOK);
  float* wgt    = (float*)(entry + 2*NTOK);
  unsigned short* xb  = (unsigned short*)(ws + (1u<<20));
  unsigned short* act = (unsigned short*)(ws + (1u<<20) + (16u<<20));
  unsigned short* wt  = (unsigned short*)(ws + (1u<<20) + (16u<<20) + (96u<<20));

  hipMemsetAsync(counts, 0, 8*sizeof(int), stream);
  k_gate<<<NTOK/4, 256, 0, stream>>>(x, gw, topi, topw, counts);
  k_scan<<<1, 64, 0, stream>>>(counts, offs, fill);
  k_scatter<<<NTOK/256, 256, 0, stream>>>(topi, topw, fill, entry, wgt);
  k_castx<<<(NTOK*DIM/4)/256, 256, 0, stream>>>(x, xb);
  k_tr<<<dim3(32, 32, 27), 256, 0, stream>>>(ew1, ew2, ew3, sw1, sw2, sw3, wt);
  k_up<<<dim3(16, 576), 256, 0, stream>>>(xb, wt, offs, entry, act);
  k_down<true><<<dim3(8, 64), 256, 0, stream>>>(act, wt, offs, entry, wgt, out);
  k_down<false><<<dim3(8, 512), 256, 0, stream>>>(act, wt, offs, entry, wgt, out);
}

// Round 4
// 1026.411 us; speedup vs baseline: 1.0213x; 1.0064x over previous
//
#include <hip/hip_runtime.h>
#include <cstdint>

#define NTOK 8192
#define DIM  1024
#define HID  2048
#define MATE (2048*1024)

typedef __attribute__((ext_vector_type(8))) short short8;
typedef __attribute__((ext_vector_type(4))) float f32x4;

typedef unsigned int __attribute__((address_space(1)))* gptr_t;
typedef unsigned int __attribute__((address_space(3)))* lptr_t;

__device__ __forceinline__ unsigned short f2bf(float f) {
  unsigned u = __builtin_bit_cast(unsigned, f);
  u += 0x7fffu + ((u >> 16) & 1u);
  return (unsigned short)(u >> 16);
}

__device__ __forceinline__ void gl_lds16(const void* g, void* l) {
  __builtin_amdgcn_global_load_lds((gptr_t)g, (lptr_t)l, 16, 0, 0);
}

#define BAR()        asm volatile("s_barrier" ::: "memory")
#define WAIT_VM(N)   asm volatile("s_waitcnt vmcnt(" #N ")" ::: "memory")
#define WAIT_LGKM0() asm volatile("s_waitcnt lgkmcnt(0)" ::: "memory")

// ---------------- gating ----------------
__global__ __launch_bounds__(256) void k_gate(const float* __restrict__ x,
    const float* __restrict__ gw, int* __restrict__ topi, float* __restrict__ topw,
    int* __restrict__ counts)
{
  int lane = threadIdx.x & 63;
  int t = blockIdx.x * 4 + (threadIdx.x >> 6);
  const float* xr = x + (size_t)t * DIM;
  float a0=0,a1=0,a2=0,a3=0,a4=0,a5=0,a6=0,a7=0;
  for (int i = 0; i < 16; ++i) {
    int idx = lane + (i << 6);
    float xv = xr[idx];
    float4 g0 = *reinterpret_cast<const float4*>(gw + idx*8);
    float4 g1 = *reinterpret_cast<const float4*>(gw + idx*8 + 4);
    a0 += xv*g0.x; a1 += xv*g0.y; a2 += xv*g0.z; a3 += xv*g0.w;
    a4 += xv*g1.x; a5 += xv*g1.y; a6 += xv*g1.z; a7 += xv*g1.w;
  }
  float acc[8] = {a0,a1,a2,a3,a4,a5,a6,a7};
  #pragma unroll
  for (int e = 0; e < 8; ++e)
    for (int off = 32; off >= 1; off >>= 1)
      acc[e] += __shfl_xor(acc[e], off, 64);
  if (lane == 0) {
    int i0 = 0; float v0 = acc[0];
    #pragma unroll
    for (int e = 1; e < 8; ++e) if (acc[e] > v0) { v0 = acc[e]; i0 = e; }
    int i1 = -1; float v1 = -3.4e38f;
    #pragma unroll
    for (int e = 0; e < 8; ++e) if (e != i0 && acc[e] > v1) { v1 = acc[e]; i1 = e; }
    float p0 = 1.f / (1.f + __expf(v1 - v0));
    topi[2*t] = i0; topi[2*t+1] = i1;
    topw[2*t] = p0; topw[2*t+1] = 1.f - p0;
    atomicAdd(&counts[i0], 1); atomicAdd(&counts[i1], 1);
  }
}

__global__ void k_scan(const int* __restrict__ counts, int* __restrict__ offs,
                       int* __restrict__ fill)
{
  if (threadIdx.x == 0) {
    int s = 0;
    for (int e = 0; e < 8; ++e) { offs[e] = s; fill[e] = s; s += counts[e]; }
    offs[8] = s;
  }
}

__global__ __launch_bounds__(256) void k_scatter(const int* __restrict__ topi,
    const float* __restrict__ topw, int* __restrict__ fill,
    int* __restrict__ entry, float* __restrict__ wgt)
{
  int t = blockIdx.x * 256 + threadIdx.x;
  #pragma unroll
  for (int k = 0; k < 2; ++k) {
    int e = topi[2*t + k];
    int pos = atomicAdd(&fill[e], 1);
    entry[pos] = t;
    wgt[pos] = topw[2*t + k];
  }
}

// ---------------- x -> bf16 ----------------
__global__ __launch_bounds__(256) void k_castx(const float* __restrict__ x,
    unsigned short* __restrict__ xb)
{
  int i = blockIdx.x * 256 + threadIdx.x;
  float4 v = reinterpret_cast<const float4*>(x)[i];
  ushort4 o; o.x = f2bf(v.x); o.y = f2bf(v.y); o.z = f2bf(v.z); o.w = f2bf(v.w);
  reinterpret_cast<ushort4*>(xb)[i] = o;
}

// ------------- weight transpose+cast: src f32 [R][C] -> dst bf16 [C][R] -------------
__global__ __launch_bounds__(256) void k_tr(const float* __restrict__ ew1,
    const float* __restrict__ ew2, const float* __restrict__ ew3,
    const float* __restrict__ sw1, const float* __restrict__ sw2,
    const float* __restrict__ sw3, unsigned short* __restrict__ wt)
{
  int z = blockIdx.z;
  const float* src; int R, C;
  if (z < 8)        { src = ew1 + (size_t)z * MATE;      R = 1024; C = 2048; }
  else if (z < 16)  { src = ew2 + (size_t)(z-8) * MATE;  R = 1024; C = 2048; }
  else if (z < 24)  { src = ew3 + (size_t)(z-16) * MATE; R = 2048; C = 1024; }
  else if (z == 24) { src = sw1; R = 1024; C = 2048; }
  else if (z == 25) { src = sw2; R = 1024; C = 2048; }
  else              { src = sw3; R = 2048; C = 1024; }
  unsigned short* dst = wt + (size_t)z * MATE;
  int cb = blockIdx.x * 64, rb = blockIdx.y * 64;
  if (cb >= C || rb >= R) return;
  __shared__ float tile[64][65];
  int tid = threadIdx.x;
  int lr = tid >> 4, lc = (tid & 15) * 4;
  #pragma unroll
  for (int i = 0; i < 4; ++i) {
    int r = lr + i*16;
    float4 v = *reinterpret_cast<const float4*>(src + (size_t)(rb + r) * C + cb + lc);
    tile[r][lc] = v.x; tile[r][lc+1] = v.y; tile[r][lc+2] = v.z; tile[r][lc+3] = v.w;
  }
  __syncthreads();
  #pragma unroll
  for (int i = 0; i < 4; ++i) {
    int c = lr + i*16;
    int r = lc;
    ushort4 o;
    o.x = f2bf(tile[r][c]);   o.y = f2bf(tile[r+1][c]);
    o.z = f2bf(tile[r+2][c]); o.w = f2bf(tile[r+3][c]);
    *reinterpret_cast<ushort4*>(dst + (size_t)(cb + c) * R + rb + r) = o;
  }
}

// ------------- up-proj (dual-B) + SwiGLU -> act bf16, counted-vmcnt 2-phase -------------
__global__ __launch_bounds__(256) void k_up(const unsigned short* __restrict__ xb,
    const unsigned short* __restrict__ wt, const int* __restrict__ offs,
    const int* __restrict__ entry, unsigned short* __restrict__ act)
{
  __shared__ __align__(16) unsigned short Al[2][128*32];
  __shared__ __align__(16) unsigned short B1l[2][128*32];
  __shared__ __align__(16) unsigned short B2l[2][128*32];
  int tid = threadIdx.x, lane = tid & 63, w = tid >> 6;
  int nb = blockIdx.x, yb = blockIdx.y;
  int mbase, mend, arow0; const unsigned short *w1, *w2; bool is_sh;
  if (yb < 512) {
    int seg = yb >> 6, mb = yb & 63;
    int s0 = offs[seg], s1 = offs[seg+1];
    mbase = s0 + mb*128;
    if (mbase >= s1) return;
    mend = s1; arow0 = mbase;
    w1 = wt + (size_t)seg * MATE; w2 = wt + (size_t)(8+seg) * MATE; is_sh = false;
  } else {
    int mb = yb - 512; mbase = mb*128; mend = NTOK; arow0 = 16384 + mbase;
    w1 = wt + (size_t)24 * MATE; w2 = wt + (size_t)25 * MATE; is_sh = true;
  }
  int r0 = w*32 + (lane >> 2), r1 = r0 + 16;
  int m0 = mbase + r0, m1 = mbase + r1;
  int tokA0 = is_sh ? m0 : ((m0 < mend) ? entry[m0] : 0);
  int tokA1 = is_sh ? m1 : ((m1 < mend) ? entry[m1] : 0);
  // pre-swizzled global chunk: (lane&3) ^ ((row>>1)&3), (row>>1)&3 == (lane>>3)&3
  int g4 = (((lane & 3) ^ ((lane >> 3) & 3))) * 8;
  const unsigned short* ga0 = xb + (size_t)tokA0 * DIM + g4;
  const unsigned short* ga1 = xb + (size_t)tokA1 * DIM + g4;
  int n0 = nb * 128;
  const unsigned short* gb1a = w1 + (size_t)(n0 + r0) * DIM + g4;
  const unsigned short* gb1b = w1 + (size_t)(n0 + r1) * DIM + g4;
  const unsigned short* gb2a = w2 + (size_t)(n0 + r0) * DIM + g4;
  const unsigned short* gb2b = w2 + (size_t)(n0 + r1) * DIM + g4;
  unsigned loff0 = (unsigned)__builtin_amdgcn_readfirstlane(w * 2048);
  unsigned loff1 = loff0 + 1024;
  int r16 = lane & 15, kg = lane >> 4, wr = w >> 1, wc = w & 1;
  int rswz = (r16 >> 1) & 3;   // (row>>1)&3 for rows of form 16a + r16
  int aoff[4], boff[4];
  #pragma unroll
  for (int m = 0; m < 4; ++m)
    aoff[m] = ((wr*64 + m*16 + r16)*4 + (kg ^ rswz)) * 16;
  #pragma unroll
  for (int n = 0; n < 4; ++n)
    boff[n] = ((wc*64 + n*16 + r16)*4 + (kg ^ rswz)) * 16;
  const f32x4 fz = {0.f, 0.f, 0.f, 0.f};
  f32x4 acc1[4][4], acc2[4][4];
  #pragma unroll
  for (int m = 0; m < 4; ++m)
    #pragma unroll
    for (int n = 0; n < 4; ++n) { acc1[m][n] = fz; acc2[m][n] = fz; }

  // prologue: issue tile 0 (6 loads in flight)
  gl_lds16(ga0,  (char*)&Al[0][0]  + loff0);
  gl_lds16(ga1,  (char*)&Al[0][0]  + loff1);
  gl_lds16(gb1a, (char*)&B1l[0][0] + loff0);
  gl_lds16(gb1b, (char*)&B1l[0][0] + loff1);
  gl_lds16(gb2a, (char*)&B2l[0][0] + loff0);
  gl_lds16(gb2b, (char*)&B2l[0][0] + loff1);

  #pragma unroll 2
  for (int t = 0; t < 32; ++t) {
    int cur = t & 1;
    if (t < 31) {
      int kn = (t + 1) * 32;
      char* ab  = (char*)&Al[cur ^ 1][0];
      char* b1b = (char*)&B1l[cur ^ 1][0];
      char* b2b = (char*)&B2l[cur ^ 1][0];
      gl_lds16(ga0 + kn,  ab  + loff0);
      gl_lds16(ga1 + kn,  ab  + loff1);
      gl_lds16(gb1a + kn, b1b + loff0);
      gl_lds16(gb1b + kn, b1b + loff1);
      gl_lds16(gb2a + kn, b2b + loff0);
      gl_lds16(gb2b + kn, b2b + loff1);
      WAIT_VM(6);   // tile t landed; tile t+1's 6 loads stay in flight
    } else {
      WAIT_VM(0);   // last tile: nothing else outstanding
    }
    BAR();          // all waves' tile-t data visible
    const char* Ab  = (const char*)&Al[cur][0];
    const char* B1b = (const char*)&B1l[cur][0];
    const char* B2b = (const char*)&B2l[cur][0];
    short8 a[4], b1v[4], b2v[4];
    #pragma unroll
    for (int m = 0; m < 4; ++m) a[m] = *(const short8*)(Ab + aoff[m]);
    #pragma unroll
    for (int n = 0; n < 4; ++n) {
      b1v[n] = *(const short8*)(B1b + boff[n]);
      b2v[n] = *(const short8*)(B2b + boff[n]);
    }
    #pragma unroll
    for (int m = 0; m < 4; ++m)
      #pragma unroll
      for (int n = 0; n < 4; ++n) {
        acc1[m][n] = __builtin_amdgcn_mfma_f32_16x16x32_bf16(a[m], b1v[n], acc1[m][n], 0, 0, 0);
        acc2[m][n] = __builtin_amdgcn_mfma_f32_16x16x32_bf16(a[m], b2v[n], acc2[m][n], 0, 0, 0);
      }
    WAIT_LGKM0();   // all my ds_reads of buf[cur] complete
    BAR();          // everyone done reading buf[cur] -> safe to overwrite next iter
  }
  #pragma unroll
  for (int m = 0; m < 4; ++m) {
    int trb = wr*64 + m*16 + kg*4;
    #pragma unroll
    for (int n = 0; n < 4; ++n) {
      int col = n0 + wc*64 + n*16 + r16;
      #pragma unroll
      for (int j = 0; j < 4; ++j) {
        int tr = trb + j;
        if (mbase + tr < mend) {
          float h1 = acc1[m][n][j], h2 = acc2[m][n][j];
          float sv = h1 / (1.f + __expf(-h1)) * h2;
          act[(size_t)(arow0 + tr) * HID + col] = f2bf(sv);
        }
      }
    }
  }
}

// ------------- down-proj: act @ w3^T -> out, counted-vmcnt 2-phase -------------
template<bool SH>
__global__ __launch_bounds__(256) void k_down(const unsigned short* __restrict__ act,
    const unsigned short* __restrict__ wt, const int* __restrict__ offs,
    const int* __restrict__ entry, const float* __restrict__ wgt,
    float* __restrict__ out)
{
  __shared__ __align__(16) unsigned short Al[2][128*32];
  __shared__ __align__(16) unsigned short Bl[2][128*32];
  int tid = threadIdx.x, lane = tid & 63, w = tid >> 6;
  int nb = blockIdx.x, yb = blockIdx.y;
  int mbase, mend, arow0; const unsigned short* w3;
  if (SH) {
    mbase = yb*128; mend = NTOK; arow0 = 16384 + mbase;
    w3 = wt + (size_t)26 * MATE;
  } else {
    int seg = yb >> 6, mb = yb & 63;
    int s0 = offs[seg], s1 = offs[seg+1];
    mbase = s0 + mb*128;
    if (mbase >= s1) return;
    mend = s1; arow0 = mbase;
    w3 = wt + (size_t)(16+seg) * MATE;
  }
  int r0 = w*32 + (lane >> 2), r1 = r0 + 16;
  int g4 = (((lane & 3) ^ ((lane >> 3) & 3))) * 8;
  const unsigned short* ga0 = act + (size_t)(arow0 + r0) * HID + g4;
  const unsigned short* ga1 = act + (size_t)(arow0 + r1) * HID + g4;
  int n0 = nb * 128;
  const unsigned short* gb0 = w3 + (size_t)(n0 + r0) * HID + g4;
  const unsigned short* gb1 = w3 + (size_t)(n0 + r1) * HID + g4;
  unsigned loff0 = (unsigned)__builtin_amdgcn_readfirstlane(w * 2048);
  unsigned loff1 = loff0 + 1024;
  int r16 = lane & 15, kg = lane >> 4, wr = w >> 1, wc = w & 1;
  int rswz = (r16 >> 1) & 3;
  int aoff[4], boff[4];
  #pragma unroll
  for (int m = 0; m < 4; ++m)
    aoff[m] = ((wr*64 + m*16 + r16)*4 + (kg ^ rswz)) * 16;
  #pragma unroll
  for (int n = 0; n < 4; ++n)
    boff[n] = ((wc*64 + n*16 + r16)*4 + (kg ^ rswz)) * 16;
  const f32x4 fz = {0.f, 0.f, 0.f, 0.f};
  f32x4 acc[4][4];
  #pragma unroll
  for (int m = 0; m < 4; ++m)
    #pragma unroll
    for (int n = 0; n < 4; ++n) acc[m][n] = fz;

  gl_lds16(ga0, (char*)&Al[0][0] + loff0);
  gl_lds16(ga1, (char*)&Al[0][0] + loff1);
  gl_lds16(gb0, (char*)&Bl[0][0] + loff0);
  gl_lds16(gb1, (char*)&Bl[0][0] + loff1);

  #pragma unroll 2
  for (int t = 0; t < 64; ++t) {
    int cur = t & 1;
    if (t < 63) {
      int kn = (t + 1) * 32;
      char* ab = (char*)&Al[cur ^ 1][0];
      char* bb = (char*)&Bl[cur ^ 1][0];
      gl_lds16(ga0 + kn, ab + loff0);
      gl_lds16(ga1 + kn, ab + loff1);
      gl_lds16(gb0 + kn, bb + loff0);
      gl_lds16(gb1 + kn, bb + loff1);
      WAIT_VM(4);
    } else {
      WAIT_VM(0);
    }
    BAR();
    const char* Ab = (const char*)&Al[cur][0];
    const char* Bb = (const char*)&Bl[cur][0];
    short8 a[4], b[4];
    #pragma unroll
    for (int m = 0; m < 4; ++m) a[m] = *(const short8*)(Ab + aoff[m]);
    #pragma unroll
    for (int n = 0; n < 4; ++n) b[n] = *(const short8*)(Bb + boff[n]);
    #pragma unroll
    for (int m = 0; m < 4; ++m)
      #pragma unroll
      for (int n = 0; n < 4; ++n)
        acc[m][n] = __builtin_amdgcn_mfma_f32_16x16x32_bf16(a[m], b[n], acc[m][n], 0, 0, 0);
    WAIT_LGKM0();
    BAR();
  }
  #pragma unroll
  for (int m = 0; m < 4; ++m) {
    int trb = wr*64 + m*16 + kg*4;
    #pragma unroll
    for (int n = 0; n < 4; ++n) {
      int col = n0 + wc*64 + n*16 + r16;
      #pragma unroll
      for (int j = 0; j < 4; ++j) {
        int tr = trb + j;
        if (mbase + tr < mend) {
          float val = acc[m][n][j];
          if (SH) {
            out[(size_t)(mbase + tr) * DIM + col] = val;
          } else {
            int tok = entry[arow0 + tr];
            float gv = wgt[arow0 + tr];
            atomicAdd(&out[(size_t)tok * DIM + col], val * gv);
          }
        }
      }
    }
  }
}

extern "C" void kernel_launch(void* const* d_in, const int* in_sizes, int n_in,
                              void* d_out, int out_size, void* d_ws, size_t ws_size,
                              hipStream_t stream)
{
  const float* x   = (const float*)d_in[0];
  const float* gw  = (const float*)d_in[1];
  const float* ew1 = (const float*)d_in[2];
  const float* ew2 = (const float*)d_in[3];
  const float* ew3 = (const float*)d_in[4];
  const float* sw1 = (const float*)d_in[5];
  const float* sw2 = (const float*)d_in[6];
  const float* sw3 = (const float*)d_in[7];
  float* out = (float*)d_out;
  char* ws = (char*)d_ws;

  int*   counts = (int*)ws;
  int*   offs   = counts + 8;
  int*   fill   = offs + 9;
  int*   topi   = fill + 8;
  float* topw   = (float*)(topi + 2*NTOK);
  int*   entry  = (int*)(topw + 2*NTOK);
  float* wgt    = (float*)(entry + 2*NTOK);
  unsigned short* xb  = (unsigned short*)(ws + (1u<<20));
  unsigned short* act = (unsigned short*)(ws + (1u<<20) + (16u<<20));
  unsigned short* wt  = (unsigned short*)(ws + (1u<<20) + (16u<<20) + (96u<<20));

  hipMemsetAsync(counts, 0, 8*sizeof(int), stream);
  k_gate<<<NTOK/4, 256, 0, stream>>>(x, gw, topi, topw, counts);
  k_scan<<<1, 64, 0, stream>>>(counts, offs, fill);
  k_scatter<<<NTOK/256, 256, 0, stream>>>(topi, topw, fill, entry, wgt);
  k_castx<<<(NTOK*DIM/4)/256, 256, 0, stream>>>(x, xb);
  k_tr<<<dim3(32, 32, 27), 256, 0, stream>>>(ew1, ew2, ew3, sw1, sw2, sw3, wt);
  k_up<<<dim3(16, 576), 256, 0, stream>>>(xb, wt, offs, entry, act);
  k_down<true><<<dim3(8, 64), 256, 0, stream>>>(act, wt, offs, entry, wgt, out);
  k_down<false><<<dim3(8, 512), 256, 0, stream>>>(act, wt, offs, entry, wgt, out);
}

// Round 6
// 993.674 us; speedup vs baseline: 1.0550x; 1.0329x over previous
//
#include <hip/hip_runtime.h>
#include <cstdint>

#define NTOK 8192
#define DIM  1024
#define HID  2048
#define MATE (2048*1024)

typedef __attribute__((ext_vector_type(8))) short short8;
typedef __attribute__((ext_vector_type(4))) float f32x4;

typedef unsigned int __attribute__((address_space(1)))* gptr_t;
typedef unsigned int __attribute__((address_space(3)))* lptr_t;

__device__ __forceinline__ unsigned short f2bf(float f) {
  unsigned u = __builtin_bit_cast(unsigned, f);
  u += 0x7fffu + ((u >> 16) & 1u);
  return (unsigned short)(u >> 16);
}

__device__ __forceinline__ void gl_lds16(const void* g, void* l) {
  __builtin_amdgcn_global_load_lds((gptr_t)g, (lptr_t)l, 16, 0, 0);
}

#define BAR()        asm volatile("s_barrier" ::: "memory")
#define WAIT_VM0()   asm volatile("s_waitcnt vmcnt(0)" ::: "memory")

// ---------------- gating ----------------
__global__ __launch_bounds__(256) void k_gate(const float* __restrict__ x,
    const float* __restrict__ gw, int* __restrict__ topi, float* __restrict__ topw,
    int* __restrict__ counts)
{
  int lane = threadIdx.x & 63;
  int t = blockIdx.x * 4 + (threadIdx.x >> 6);
  const float* xr = x + (size_t)t * DIM;
  float a0=0,a1=0,a2=0,a3=0,a4=0,a5=0,a6=0,a7=0;
  for (int i = 0; i < 16; ++i) {
    int idx = lane + (i << 6);
    float xv = xr[idx];
    float4 g0 = *reinterpret_cast<const float4*>(gw + idx*8);
    float4 g1 = *reinterpret_cast<const float4*>(gw + idx*8 + 4);
    a0 += xv*g0.x; a1 += xv*g0.y; a2 += xv*g0.z; a3 += xv*g0.w;
    a4 += xv*g1.x; a5 += xv*g1.y; a6 += xv*g1.z; a7 += xv*g1.w;
  }
  float acc[8] = {a0,a1,a2,a3,a4,a5,a6,a7};
  #pragma unroll
  for (int e = 0; e < 8; ++e)
    for (int off = 32; off >= 1; off >>= 1)
      acc[e] += __shfl_xor(acc[e], off, 64);
  if (lane == 0) {
    int i0 = 0; float v0 = acc[0];
    #pragma unroll
    for (int e = 1; e < 8; ++e) if (acc[e] > v0) { v0 = acc[e]; i0 = e; }
    int i1 = -1; float v1 = -3.4e38f;
    #pragma unroll
    for (int e = 0; e < 8; ++e) if (e != i0 && acc[e] > v1) { v1 = acc[e]; i1 = e; }
    float p0 = 1.f / (1.f + __expf(v1 - v0));
    topi[2*t] = i0; topi[2*t+1] = i1;
    topw[2*t] = p0; topw[2*t+1] = 1.f - p0;
    atomicAdd(&counts[i0], 1); atomicAdd(&counts[i1], 1);
  }
}

__global__ void k_scan(const int* __restrict__ counts, int* __restrict__ offs,
                       int* __restrict__ fill)
{
  if (threadIdx.x == 0) {
    int s = 0;
    for (int e = 0; e < 8; ++e) { offs[e] = s; fill[e] = s; s += counts[e]; }
    offs[8] = s;
  }
}

__global__ __launch_bounds__(256) void k_scatter(const int* __restrict__ topi,
    const float* __restrict__ topw, int* __restrict__ fill,
    int* __restrict__ entry, float* __restrict__ wgt)
{
  int t = blockIdx.x * 256 + threadIdx.x;
  #pragma unroll
  for (int k = 0; k < 2; ++k) {
    int e = topi[2*t + k];
    int pos = atomicAdd(&fill[e], 1);
    entry[pos] = t;
    wgt[pos] = topw[2*t + k];
  }
}

// ---------------- x -> bf16 ----------------
__global__ __launch_bounds__(256) void k_castx(const float* __restrict__ x,
    unsigned short* __restrict__ xb)
{
  int i = blockIdx.x * 256 + threadIdx.x;
  float4 v = reinterpret_cast<const float4*>(x)[i];
  ushort4 o; o.x = f2bf(v.x); o.y = f2bf(v.y); o.z = f2bf(v.z); o.w = f2bf(v.w);
  reinterpret_cast<ushort4*>(xb)[i] = o;
}

// ------------- weight transpose+cast: src f32 [R][C] -> dst bf16 [C][R] -------------
__global__ __launch_bounds__(256) void k_tr(const float* __restrict__ ew1,
    const float* __restrict__ ew2, const float* __restrict__ ew3,
    const float* __restrict__ sw1, const float* __restrict__ sw2,
    const float* __restrict__ sw3, unsigned short* __restrict__ wt)
{
  int z = blockIdx.z;
  const float* src; int R, C;
  if (z < 8)        { src = ew1 + (size_t)z * MATE;      R = 1024; C = 2048; }
  else if (z < 16)  { src = ew2 + (size_t)(z-8) * MATE;  R = 1024; C = 2048; }
  else if (z < 24)  { src = ew3 + (size_t)(z-16) * MATE; R = 2048; C = 1024; }
  else if (z == 24) { src = sw1; R = 1024; C = 2048; }
  else if (z == 25) { src = sw2; R = 1024; C = 2048; }
  else              { src = sw3; R = 2048; C = 1024; }
  unsigned short* dst = wt + (size_t)z * MATE;
  int cb = blockIdx.x * 64, rb = blockIdx.y * 64;
  if (cb >= C || rb >= R) return;
  __shared__ float tile[64][65];
  int tid = threadIdx.x;
  int lr = tid >> 4, lc = (tid & 15) * 4;
  #pragma unroll
  for (int i = 0; i < 4; ++i) {
    int r = lr + i*16;
    float4 v = *reinterpret_cast<const float4*>(src + (size_t)(rb + r) * C + cb + lc);
    tile[r][lc] = v.x; tile[r][lc+1] = v.y; tile[r][lc+2] = v.z; tile[r][lc+3] = v.w;
  }
  __syncthreads();
  #pragma unroll
  for (int i = 0; i < 4; ++i) {
    int c = lr + i*16;
    int r = lc;
    ushort4 o;
    o.x = f2bf(tile[r][c]);   o.y = f2bf(tile[r+1][c]);
    o.z = f2bf(tile[r+2][c]); o.w = f2bf(tile[r+3][c]);
    *reinterpret_cast<ushort4*>(dst + (size_t)(cb + c) * R + rb + r) = o;
  }
}

// ============ up-proj (dual-B) + SwiGLU, BM=256/BN=128x2/BK=64, 1-barrier 2-phase ============
// 512 threads = 8 waves (4M x 2N). LDS/buf 64KB: A[256][64]@0, B1[128][64]@32768, B2@49152.
// XOR swizzle: LDS chunk c of row r holds global chunk c^(r&7) (16B chunks).
__global__ __launch_bounds__(512, 2) void k_up(const unsigned short* __restrict__ xb,
    const unsigned short* __restrict__ wt, const int* __restrict__ offs,
    const int* __restrict__ entry, unsigned short* __restrict__ act)
{
  __shared__ __align__(16) unsigned short L[2][32768];   // 128 KB
  int tid = threadIdx.x, lane = tid & 63, w = tid >> 6;
  int nb = blockIdx.x, yb = blockIdx.y;
  int mbase, mend, arow0; const unsigned short *w1, *w2; bool is_sh;
  if (yb < 256) {
    int seg = yb >> 5, mb = yb & 31;
    int s0 = offs[seg], s1 = offs[seg+1];
    mbase = s0 + mb*256; if (mbase >= s1) return;
    mend = s1; arow0 = mbase;
    w1 = wt + (size_t)seg * MATE; w2 = wt + (size_t)(8+seg) * MATE; is_sh = false;
  } else {
    int mb = yb - 256; mbase = mb*256; mend = NTOK; arow0 = 16384 + mbase;
    w1 = wt + (size_t)24 * MATE; w2 = wt + (size_t)25 * MATE; is_sh = true;
  }
  int l8 = lane >> 3;
  int swz8 = ((lane & 7) ^ l8) * 8;          // pre-swizzled global chunk offset (elems)
  const unsigned short* pA[4];
  #pragma unroll
  for (int j = 0; j < 4; ++j) {
    int mi = mbase + j*64 + w*8 + l8;
    int tok = is_sh ? mi : ((mi < mend) ? entry[mi] : 0);
    pA[j] = xb + (size_t)tok * DIM + swz8;
  }
  int n0 = nb * 128;
  const unsigned short *pB1[2], *pB2[2];
  #pragma unroll
  for (int j = 0; j < 2; ++j) {
    int r = n0 + j*64 + w*8 + l8;
    pB1[j] = w1 + (size_t)r * DIM + swz8;
    pB2[j] = w2 + (size_t)r * DIM + swz8;
  }
  unsigned wq = (unsigned)__builtin_amdgcn_readfirstlane(w * 1024u);
  int r16 = lane & 15, kg = lane >> 4, wm = w >> 1, wn = w & 1;
  int xr = r16 & 7;
  int rdA = (wm*64 + r16)*128 + ((kg ^ xr) << 4);   // byte offset, kk0; kk1 = ^64
  int rdB = (wn*64 + r16)*128 + ((kg ^ xr) << 4);
  const f32x4 fz = {0.f,0.f,0.f,0.f};
  f32x4 acc1[4][4], acc2[4][4];
  #pragma unroll
  for (int m = 0; m < 4; ++m)
    #pragma unroll
    for (int n = 0; n < 4; ++n) { acc1[m][n] = fz; acc2[m][n] = fz; }

  auto STAGE = [&](char* S, int kn) {
    gl_lds16(pA[0]  + kn, S + 0     + wq);
    gl_lds16(pA[1]  + kn, S + 8192  + wq);
    gl_lds16(pA[2]  + kn, S + 16384 + wq);
    gl_lds16(pA[3]  + kn, S + 24576 + wq);
    gl_lds16(pB1[0] + kn, S + 32768 + wq);
    gl_lds16(pB1[1] + kn, S + 40960 + wq);
    gl_lds16(pB2[0] + kn, S + 49152 + wq);
    gl_lds16(pB2[1] + kn, S + 57344 + wq);
  };

  STAGE((char*)&L[0][0], 0);
  WAIT_VM0(); BAR();
  const char* Bp = (const char*)&L[0][0];
  char* Sp = (char*)&L[1][0];

  #pragma unroll 2
  for (int t = 0; t < 16; ++t) {
    // all ds_reads first (never after a gl_lds in source order)
    short8 a0[4], a1[4], b10[4], b11[4], b20[4], b21[4];
    #pragma unroll
    for (int m = 0; m < 4; ++m) {
      a0[m] = *(const short8*)(Bp + rdA + m*2048);
      a1[m] = *(const short8*)(Bp + (rdA^64) + m*2048);
    }
    #pragma unroll
    for (int n = 0; n < 4; ++n) {
      b10[n] = *(const short8*)(Bp + 32768 + rdB + n*2048);
      b11[n] = *(const short8*)(Bp + 32768 + (rdB^64) + n*2048);
      b20[n] = *(const short8*)(Bp + 49152 + rdB + n*2048);
      b21[n] = *(const short8*)(Bp + 49152 + (rdB^64) + n*2048);
    }
    if (t < 15) STAGE(Sp, (t + 1) * 64);
    #pragma unroll
    for (int m = 0; m < 4; ++m)
      #pragma unroll
      for (int n = 0; n < 4; ++n) {
        acc1[m][n] = __builtin_amdgcn_mfma_f32_16x16x32_bf16(a0[m], b10[n], acc1[m][n], 0, 0, 0);
        acc2[m][n] = __builtin_amdgcn_mfma_f32_16x16x32_bf16(a0[m], b20[n], acc2[m][n], 0, 0, 0);
      }
    #pragma unroll
    for (int m = 0; m < 4; ++m)
      #pragma unroll
      for (int n = 0; n < 4; ++n) {
        acc1[m][n] = __builtin_amdgcn_mfma_f32_16x16x32_bf16(a1[m], b11[n], acc1[m][n], 0, 0, 0);
        acc2[m][n] = __builtin_amdgcn_mfma_f32_16x16x32_bf16(a1[m], b21[n], acc2[m][n], 0, 0, 0);
      }
    WAIT_VM0();   // my staging writes into Sp landed
    BAR();        // + everyone's reads of Bp done (their lgkm waits precede their MFMA/bar)
    char* tmp = (char*)Bp; Bp = Sp; Sp = tmp;
  }
  // epilogue: silu(h1)*h2 -> act
  #pragma unroll
  for (int m = 0; m < 4; ++m) {
    int trb = wm*64 + m*16 + kg*4;
    #pragma unroll
    for (int n = 0; n < 4; ++n) {
      int col = n0 + wn*64 + n*16 + r16;
      #pragma unroll
      for (int j = 0; j < 4; ++j) {
        int tr = trb + j;
        if (mbase + tr < mend) {
          float h1 = acc1[m][n][j], h2 = acc2[m][n][j];
          float sv = h1 / (1.f + __expf(-h1)) * h2;
          act[(size_t)(arow0 + tr) * HID + col] = f2bf(sv);
        }
      }
    }
  }
}

// ============ down-proj, BM=256/BN=128/BK=64, 1-barrier 2-phase ============
// 512 threads = 8 waves (4M x 2N). LDS/buf 48KB: A[256][64]@0, B[128][64]@32768.
template<bool SH>
__global__ __launch_bounds__(512, 2) void k_down(const unsigned short* __restrict__ act,
    const unsigned short* __restrict__ wt, const int* __restrict__ offs,
    const int* __restrict__ entry, const float* __restrict__ wgt,
    float* __restrict__ out)
{
  __shared__ __align__(16) unsigned short L[2][24576];   // 96 KB
  int tid = threadIdx.x, lane = tid & 63, w = tid >> 6;
  int nb = blockIdx.x, yb = blockIdx.y;
  int mbase, mend, arow0; const unsigned short* w3;
  if (SH) {
    mbase = yb*256; mend = NTOK; arow0 = 16384 + mbase;
    w3 = wt + (size_t)26 * MATE;
  } else {
    int seg = yb >> 5, mb = yb & 31;
    int s0 = offs[seg], s1 = offs[seg+1];
    mbase = s0 + mb*256; if (mbase >= s1) return;
    mend = s1; arow0 = mbase;
    w3 = wt + (size_t)(16+seg) * MATE;
  }
  int l8 = lane >> 3;
  int swz8 = ((lane & 7) ^ l8) * 8;
  const unsigned short* pA[4];
  #pragma unroll
  for (int j = 0; j < 4; ++j)
    pA[j] = act + (size_t)(arow0 + j*64 + w*8 + l8) * HID + swz8;
  int n0b = nb * 128;
  const unsigned short* pB[2];
  #pragma unroll
  for (int j = 0; j < 2; ++j)
    pB[j] = w3 + (size_t)(n0b + j*64 + w*8 + l8) * HID + swz8;
  unsigned wq = (unsigned)__builtin_amdgcn_readfirstlane(w * 1024u);
  int r16 = lane & 15, kg = lane >> 4, wm = w >> 1, wn = w & 1;
  int xr = r16 & 7;
  int rdA = (wm*64 + r16)*128 + ((kg ^ xr) << 4);
  int rdB = (wn*64 + r16)*128 + ((kg ^ xr) << 4);
  const f32x4 fz = {0.f,0.f,0.f,0.f};
  f32x4 acc[4][4];
  #pragma unroll
  for (int m = 0; m < 4; ++m)
    #pragma unroll
    for (int n = 0; n < 4; ++n) acc[m][n] = fz;

  auto STAGE = [&](char* S, int kn) {
    gl_lds16(pA[0] + kn, S + 0     + wq);
    gl_lds16(pA[1] + kn, S + 8192  + wq);
    gl_lds16(pA[2] + kn, S + 16384 + wq);
    gl_lds16(pA[3] + kn, S + 24576 + wq);
    gl_lds16(pB[0] + kn, S + 32768 + wq);
    gl_lds16(pB[1] + kn, S + 40960 + wq);
  };

  STAGE((char*)&L[0][0], 0);
  WAIT_VM0(); BAR();
  const char* Bp = (const char*)&L[0][0];
  char* Sp = (char*)&L[1][0];

  #pragma unroll 2
  for (int t = 0; t < 32; ++t) {
    short8 a0[4], a1[4], b0[4], b1[4];
    #pragma unroll
    for (int m = 0; m < 4; ++m) {
      a0[m] = *(const short8*)(Bp + rdA + m*2048);
      a1[m] = *(const short8*)(Bp + (rdA^64) + m*2048);
    }
    #pragma unroll
    for (int n = 0; n < 4; ++n) {
      b0[n] = *(const short8*)(Bp + 32768 + rdB + n*2048);
      b1[n] = *(const short8*)(Bp + 32768 + (rdB^64) + n*2048);
    }
    if (t < 31) STAGE(Sp, (t + 1) * 64);
    #pragma unroll
    for (int m = 0; m < 4; ++m)
      #pragma unroll
      for (int n = 0; n < 4; ++n)
        acc[m][n] = __builtin_amdgcn_mfma_f32_16x16x32_bf16(a0[m], b0[n], acc[m][n], 0, 0, 0);
    #pragma unroll
    for (int m = 0; m < 4; ++m)
      #pragma unroll
      for (int n = 0; n < 4; ++n)
        acc[m][n] = __builtin_amdgcn_mfma_f32_16x16x32_bf16(a1[m], b1[n], acc[m][n], 0, 0, 0);
    WAIT_VM0();
    BAR();
    char* tmp = (char*)Bp; Bp = Sp; Sp = tmp;
  }
  #pragma unroll
  for (int m = 0; m < 4; ++m) {
    int trb = wm*64 + m*16 + kg*4;
    #pragma unroll
    for (int n = 0; n < 4; ++n) {
      int col = n0b + wn*64 + n*16 + r16;
      #pragma unroll
      for (int j = 0; j < 4; ++j) {
        int tr = trb + j;
        if (mbase + tr < mend) {
          float val = acc[m][n][j];
          if (SH) {
            out[(size_t)(mbase + tr) * DIM + col] = val;
          } else {
            int tok = entry[arow0 + tr];
            float gv = wgt[arow0 + tr];
            atomicAdd(&out[(size_t)tok * DIM + col], val * gv);
          }
        }
      }
    }
  }
}

extern "C" void kernel_launch(void* const* d_in, const int* in_sizes, int n_in,
                              void* d_out, int out_size, void* d_ws, size_t ws_size,
                              hipStream_t stream)
{
  const float* x   = (const float*)d_in[0];
  const float* gw  = (const float*)d_in[1];
  const float* ew1 = (const float*)d_in[2];
  const float* ew2 = (const float*)d_in[3];
  const float* ew3 = (const float*)d_in[4];
  const float* sw1 = (const float*)d_in[5];
  const float* sw2 = (const float*)d_in[6];
  const float* sw3 = (const float*)d_in[7];
  float* out = (float*)d_out;
  char* ws = (char*)d_ws;

  int*   counts = (int*)ws;
  int*   offs   = counts + 8;
  int*   fill   = offs + 9;
  int*   topi   = fill + 8;
  float* topw   = (float*)(topi + 2*NTOK);
  int*   entry  = (int*)(topw + 2*NTOK);
  float* wgt    = (float*)(entry + 2*NTOK);
  unsigned short* xb  = (unsigned short*)(ws + (1u<<20));
  unsigned short* act = (unsigned short*)(ws + (1u<<20) + (16u<<20));
  unsigned short* wt  = (unsigned short*)(ws + (1u<<20) + (16u<<20) + (96u<<20));

  hipMemsetAsync(counts, 0, 8*sizeof(int), stream);
  k_gate<<<NTOK/4, 256, 0, stream>>>(x, gw, topi, topw, counts);
  k_scan<<<1, 64, 0, stream>>>(counts, offs, fill);
  k_scatter<<<NTOK/256, 256, 0, stream>>>(topi, topw, fill, entry, wgt);
  k_castx<<<(NTOK*DIM/4)/256, 256, 0, stream>>>(x, xb);
  k_tr<<<dim3(32, 32, 27), 256, 0, stream>>>(ew1, ew2, ew3, sw1, sw2, sw3, wt);
  k_up<<<dim3(16, 288), 512, 0, stream>>>(xb, wt, offs, entry, act);
  k_down<true><<<dim3(8, 32), 512, 0, stream>>>(act, wt, offs, entry, wgt, out);
  k_down<false><<<dim3(8, 256), 512, 0, stream>>>(act, wt, offs, entry, wgt, out);
}

// Round 7
// 781.016 us; speedup vs baseline: 1.3422x; 1.2723x over previous
//
#include <hip/hip_runtime.h>
#include <cstdint>

#define NTOK 8192
#define DIM  1024
#define HID  2048
#define MATE (2048*1024)

typedef __attribute__((ext_vector_type(8))) short short8;
typedef __attribute__((ext_vector_type(4))) float f32x4;

typedef unsigned int __attribute__((address_space(1)))* gptr_t;
typedef unsigned int __attribute__((address_space(3)))* lptr_t;

__device__ __forceinline__ unsigned short f2bf(float f) {
  unsigned u = __builtin_bit_cast(unsigned, f);
  u += 0x7fffu + ((u >> 16) & 1u);
  return (unsigned short)(u >> 16);
}

__device__ __forceinline__ void gl_lds16(const void* g, void* l) {
  __builtin_amdgcn_global_load_lds((gptr_t)g, (lptr_t)l, 16, 0, 0);
}

#define BAR()        asm volatile("s_barrier" ::: "memory")
#define WAIT_VM0()   asm volatile("s_waitcnt vmcnt(0)" ::: "memory")

// ---------------- gating ----------------
__global__ __launch_bounds__(256) void k_gate(const float* __restrict__ x,
    const float* __restrict__ gw, int* __restrict__ topi, float* __restrict__ topw,
    int* __restrict__ counts)
{
  int lane = threadIdx.x & 63;
  int t = blockIdx.x * 4 + (threadIdx.x >> 6);
  const float* xr = x + (size_t)t * DIM;
  float a0=0,a1=0,a2=0,a3=0,a4=0,a5=0,a6=0,a7=0;
  for (int i = 0; i < 16; ++i) {
    int idx = lane + (i << 6);
    float xv = xr[idx];
    float4 g0 = *reinterpret_cast<const float4*>(gw + idx*8);
    float4 g1 = *reinterpret_cast<const float4*>(gw + idx*8 + 4);
    a0 += xv*g0.x; a1 += xv*g0.y; a2 += xv*g0.z; a3 += xv*g0.w;
    a4 += xv*g1.x; a5 += xv*g1.y; a6 += xv*g1.z; a7 += xv*g1.w;
  }
  float acc[8] = {a0,a1,a2,a3,a4,a5,a6,a7};
  #pragma unroll
  for (int e = 0; e < 8; ++e)
    for (int off = 32; off >= 1; off >>= 1)
      acc[e] += __shfl_xor(acc[e], off, 64);
  if (lane == 0) {
    int i0 = 0; float v0 = acc[0];
    #pragma unroll
    for (int e = 1; e < 8; ++e) if (acc[e] > v0) { v0 = acc[e]; i0 = e; }
    int i1 = -1; float v1 = -3.4e38f;
    #pragma unroll
    for (int e = 0; e < 8; ++e) if (e != i0 && acc[e] > v1) { v1 = acc[e]; i1 = e; }
    float p0 = 1.f / (1.f + __expf(v1 - v0));
    topi[2*t] = i0; topi[2*t+1] = i1;
    topw[2*t] = p0; topw[2*t+1] = 1.f - p0;
    atomicAdd(&counts[i0], 1); atomicAdd(&counts[i1], 1);
  }
}

__global__ void k_scan(const int* __restrict__ counts, int* __restrict__ offs,
                       int* __restrict__ fill)
{
  if (threadIdx.x == 0) {
    int s = 0;
    for (int e = 0; e < 8; ++e) { offs[e] = s; fill[e] = s; s += counts[e]; }
    offs[8] = s;
  }
}

__global__ __launch_bounds__(256) void k_scatter(const int* __restrict__ topi,
    const float* __restrict__ topw, int* __restrict__ fill,
    int* __restrict__ entry, float* __restrict__ wgt)
{
  int t = blockIdx.x * 256 + threadIdx.x;
  #pragma unroll
  for (int k = 0; k < 2; ++k) {
    int e = topi[2*t + k];
    int pos = atomicAdd(&fill[e], 1);
    entry[pos] = t;
    wgt[pos] = topw[2*t + k];
  }
}

// ---------------- x -> bf16 ----------------
__global__ __launch_bounds__(256) void k_castx(const float* __restrict__ x,
    unsigned short* __restrict__ xb)
{
  int i = blockIdx.x * 256 + threadIdx.x;
  float4 v = reinterpret_cast<const float4*>(x)[i];
  ushort4 o; o.x = f2bf(v.x); o.y = f2bf(v.y); o.z = f2bf(v.z); o.w = f2bf(v.w);
  reinterpret_cast<ushort4*>(xb)[i] = o;
}

// ------------- weight transpose+cast: src f32 [R][C] -> dst bf16 [C][R] -------------
__global__ __launch_bounds__(256) void k_tr(const float* __restrict__ ew1,
    const float* __restrict__ ew2, const float* __restrict__ ew3,
    const float* __restrict__ sw1, const float* __restrict__ sw2,
    const float* __restrict__ sw3, unsigned short* __restrict__ wt)
{
  int z = blockIdx.z;
  const float* src; int R, C;
  if (z < 8)        { src = ew1 + (size_t)z * MATE;      R = 1024; C = 2048; }
  else if (z < 16)  { src = ew2 + (size_t)(z-8) * MATE;  R = 1024; C = 2048; }
  else if (z < 24)  { src = ew3 + (size_t)(z-16) * MATE; R = 2048; C = 1024; }
  else if (z == 24) { src = sw1; R = 1024; C = 2048; }
  else if (z == 25) { src = sw2; R = 1024; C = 2048; }
  else              { src = sw3; R = 2048; C = 1024; }
  unsigned short* dst = wt + (size_t)z * MATE;
  int cb = blockIdx.x * 64, rb = blockIdx.y * 64;
  if (cb >= C || rb >= R) return;
  __shared__ float tile[64][65];
  int tid = threadIdx.x;
  int lr = tid >> 4, lc = (tid & 15) * 4;
  #pragma unroll
  for (int i = 0; i < 4; ++i) {
    int r = lr + i*16;
    float4 v = *reinterpret_cast<const float4*>(src + (size_t)(rb + r) * C + cb + lc);
    tile[r][lc] = v.x; tile[r][lc+1] = v.y; tile[r][lc+2] = v.z; tile[r][lc+3] = v.w;
  }
  __syncthreads();
  #pragma unroll
  for (int i = 0; i < 4; ++i) {
    int c = lr + i*16;
    int r = lc;
    ushort4 o;
    o.x = f2bf(tile[r][c]);   o.y = f2bf(tile[r+1][c]);
    o.z = f2bf(tile[r+2][c]); o.w = f2bf(tile[r+3][c]);
    *reinterpret_cast<ushort4*>(dst + (size_t)(cb + c) * R + rb + r) = o;
  }
}

// ============ up-proj (dual-B) + SwiGLU, BM=256/BN=128x2/BK=64, 1-barrier 2-phase ============
// 512 threads = 8 waves (4M x 2N). LDS/buf 64KB: A[256][64]@0, B1[128][64]@32768, B2@49152.
// XOR swizzle: LDS chunk c of row r holds global chunk c^(r&7) (16B chunks).
// Sub-phased fragment loads keep frag liveness at <=8 short8 (no spills).
__global__ __launch_bounds__(512, 2) void k_up(const unsigned short* __restrict__ xb,
    const unsigned short* __restrict__ wt, const int* __restrict__ offs,
    const int* __restrict__ entry, unsigned short* __restrict__ act)
{
  __shared__ __align__(16) unsigned short L[2][32768];   // 128 KB
  int tid = threadIdx.x, lane = tid & 63, w = tid >> 6;
  int nb = blockIdx.x, yb = blockIdx.y;
  int mbase, mend, arow0; const unsigned short *w1, *w2; bool is_sh;
  if (yb < 256) {
    int seg = yb >> 5, mb = yb & 31;
    int s0 = offs[seg], s1 = offs[seg+1];
    mbase = s0 + mb*256; if (mbase >= s1) return;
    mend = s1; arow0 = mbase;
    w1 = wt + (size_t)seg * MATE; w2 = wt + (size_t)(8+seg) * MATE; is_sh = false;
  } else {
    int mb = yb - 256; mbase = mb*256; mend = NTOK; arow0 = 16384 + mbase;
    w1 = wt + (size_t)24 * MATE; w2 = wt + (size_t)25 * MATE; is_sh = true;
  }
  int l8 = lane >> 3;
  int swz8 = ((lane & 7) ^ l8) * 8;          // pre-swizzled global chunk offset (elems)
  const unsigned short* pA[4];
  #pragma unroll
  for (int j = 0; j < 4; ++j) {
    int mi = mbase + j*64 + w*8 + l8;
    int tok = is_sh ? mi : ((mi < mend) ? entry[mi] : 0);
    pA[j] = xb + (size_t)tok * DIM + swz8;
  }
  int n0 = nb * 128;
  const unsigned short *pB1[2], *pB2[2];
  #pragma unroll
  for (int j = 0; j < 2; ++j) {
    int r = n0 + j*64 + w*8 + l8;
    pB1[j] = w1 + (size_t)r * DIM + swz8;
    pB2[j] = w2 + (size_t)r * DIM + swz8;
  }
  unsigned wq = (unsigned)__builtin_amdgcn_readfirstlane(w * 1024u);
  int r16 = lane & 15, kg = lane >> 4, wm = w >> 1, wn = w & 1;
  int xr = r16 & 7;
  int rdA = (wm*64 + r16)*128 + ((kg ^ xr) << 4);   // byte offset, kk0; kk1 = ^64
  int rdB = (wn*64 + r16)*128 + ((kg ^ xr) << 4);
  const f32x4 fz = {0.f,0.f,0.f,0.f};
  f32x4 acc1[4][4], acc2[4][4];
  #pragma unroll
  for (int m = 0; m < 4; ++m)
    #pragma unroll
    for (int n = 0; n < 4; ++n) { acc1[m][n] = fz; acc2[m][n] = fz; }

  auto STAGE = [&](char* S, int kn) {
    gl_lds16(pA[0]  + kn, S + 0     + wq);
    gl_lds16(pA[1]  + kn, S + 8192  + wq);
    gl_lds16(pA[2]  + kn, S + 16384 + wq);
    gl_lds16(pA[3]  + kn, S + 24576 + wq);
    gl_lds16(pB1[0] + kn, S + 32768 + wq);
    gl_lds16(pB1[1] + kn, S + 40960 + wq);
    gl_lds16(pB2[0] + kn, S + 49152 + wq);
    gl_lds16(pB2[1] + kn, S + 57344 + wq);
  };

  STAGE((char*)&L[0][0], 0);
  WAIT_VM0(); BAR();
  const char* Bp = (const char*)&L[0][0];
  char* Sp = (char*)&L[1][0];

  #pragma unroll 1
  for (int t = 0; t < 16; ++t) {
    short8 a[4], b[4];
    // ---- sub 1: A kk0 + B1 kk0 ----
    #pragma unroll
    for (int m = 0; m < 4; ++m) a[m] = *(const short8*)(Bp + rdA + m*2048);
    #pragma unroll
    for (int n = 0; n < 4; ++n) b[n] = *(const short8*)(Bp + 32768 + rdB + n*2048);
    if (t < 15) STAGE(Sp, (t + 1) * 64);
    #pragma unroll
    for (int m = 0; m < 4; ++m)
      #pragma unroll
      for (int n = 0; n < 4; ++n)
        acc1[m][n] = __builtin_amdgcn_mfma_f32_16x16x32_bf16(a[m], b[n], acc1[m][n], 0, 0, 0);
    // ---- sub 2: B2 kk0 (a still live) ----
    #pragma unroll
    for (int n = 0; n < 4; ++n) b[n] = *(const short8*)(Bp + 49152 + rdB + n*2048);
    #pragma unroll
    for (int m = 0; m < 4; ++m)
      #pragma unroll
      for (int n = 0; n < 4; ++n)
        acc2[m][n] = __builtin_amdgcn_mfma_f32_16x16x32_bf16(a[m], b[n], acc2[m][n], 0, 0, 0);
    // ---- sub 3: A kk1 + B1 kk1 ----
    #pragma unroll
    for (int m = 0; m < 4; ++m) a[m] = *(const short8*)(Bp + (rdA^64) + m*2048);
    #pragma unroll
    for (int n = 0; n < 4; ++n) b[n] = *(const short8*)(Bp + 32768 + (rdB^64) + n*2048);
    #pragma unroll
    for (int m = 0; m < 4; ++m)
      #pragma unroll
      for (int n = 0; n < 4; ++n)
        acc1[m][n] = __builtin_amdgcn_mfma_f32_16x16x32_bf16(a[m], b[n], acc1[m][n], 0, 0, 0);
    // ---- sub 4: B2 kk1 ----
    #pragma unroll
    for (int n = 0; n < 4; ++n) b[n] = *(const short8*)(Bp + 49152 + (rdB^64) + n*2048);
    #pragma unroll
    for (int m = 0; m < 4; ++m)
      #pragma unroll
      for (int n = 0; n < 4; ++n)
        acc2[m][n] = __builtin_amdgcn_mfma_f32_16x16x32_bf16(a[m], b[n], acc2[m][n], 0, 0, 0);
    WAIT_VM0();   // my staging writes into Sp landed
    BAR();        // + everyone's reads of Bp done (lgkm waits precede their MFMAs)
    char* tmp = (char*)Bp; Bp = Sp; Sp = tmp;
  }
  // epilogue: silu(h1)*h2 -> act
  #pragma unroll
  for (int m = 0; m < 4; ++m) {
    int trb = wm*64 + m*16 + kg*4;
    #pragma unroll
    for (int n = 0; n < 4; ++n) {
      int col = n0 + wn*64 + n*16 + r16;
      #pragma unroll
      for (int j = 0; j < 4; ++j) {
        int tr = trb + j;
        if (mbase + tr < mend) {
          float h1 = acc1[m][n][j], h2 = acc2[m][n][j];
          float sv = h1 / (1.f + __expf(-h1)) * h2;
          act[(size_t)(arow0 + tr) * HID + col] = f2bf(sv);
        }
      }
    }
  }
}

// ============ down-proj, BM=256/BN=128/BK=64, 1-barrier 2-phase ============
// 512 threads = 8 waves (4M x 2N). LDS/buf 48KB: A[256][64]@0, B[128][64]@32768.
template<bool SH>
__global__ __launch_bounds__(512, 2) void k_down(const unsigned short* __restrict__ act,
    const unsigned short* __restrict__ wt, const int* __restrict__ offs,
    const int* __restrict__ entry, const float* __restrict__ wgt,
    float* __restrict__ out)
{
  __shared__ __align__(16) unsigned short L[2][24576];   // 96 KB
  int tid = threadIdx.x, lane = tid & 63, w = tid >> 6;
  int nb = blockIdx.x, yb = blockIdx.y;
  int mbase, mend, arow0; const unsigned short* w3;
  if (SH) {
    mbase = yb*256; mend = NTOK; arow0 = 16384 + mbase;
    w3 = wt + (size_t)26 * MATE;
  } else {
    int seg = yb >> 5, mb = yb & 31;
    int s0 = offs[seg], s1 = offs[seg+1];
    mbase = s0 + mb*256; if (mbase >= s1) return;
    mend = s1; arow0 = mbase;
    w3 = wt + (size_t)(16+seg) * MATE;
  }
  int l8 = lane >> 3;
  int swz8 = ((lane & 7) ^ l8) * 8;
  const unsigned short* pA[4];
  #pragma unroll
  for (int j = 0; j < 4; ++j)
    pA[j] = act + (size_t)(arow0 + j*64 + w*8 + l8) * HID + swz8;
  int n0b = nb * 128;
  const unsigned short* pB[2];
  #pragma unroll
  for (int j = 0; j < 2; ++j)
    pB[j] = w3 + (size_t)(n0b + j*64 + w*8 + l8) * HID + swz8;
  unsigned wq = (unsigned)__builtin_amdgcn_readfirstlane(w * 1024u);
  int r16 = lane & 15, kg = lane >> 4, wm = w >> 1, wn = w & 1;
  int xr = r16 & 7;
  int rdA = (wm*64 + r16)*128 + ((kg ^ xr) << 4);
  int rdB = (wn*64 + r16)*128 + ((kg ^ xr) << 4);
  const f32x4 fz = {0.f,0.f,0.f,0.f};
  f32x4 acc[4][4];
  #pragma unroll
  for (int m = 0; m < 4; ++m)
    #pragma unroll
    for (int n = 0; n < 4; ++n) acc[m][n] = fz;

  auto STAGE = [&](char* S, int kn) {
    gl_lds16(pA[0] + kn, S + 0     + wq);
    gl_lds16(pA[1] + kn, S + 8192  + wq);
    gl_lds16(pA[2] + kn, S + 16384 + wq);
    gl_lds16(pA[3] + kn, S + 24576 + wq);
    gl_lds16(pB[0] + kn, S + 32768 + wq);
    gl_lds16(pB[1] + kn, S + 40960 + wq);
  };

  STAGE((char*)&L[0][0], 0);
  WAIT_VM0(); BAR();
  const char* Bp = (const char*)&L[0][0];
  char* Sp = (char*)&L[1][0];

  #pragma unroll 1
  for (int t = 0; t < 32; ++t) {
    short8 a[4], b[4];
    // ---- sub 1: kk0 ----
    #pragma unroll
    for (int m = 0; m < 4; ++m) a[m] = *(const short8*)(Bp + rdA + m*2048);
    #pragma unroll
    for (int n = 0; n < 4; ++n) b[n] = *(const short8*)(Bp + 32768 + rdB + n*2048);
    if (t < 31) STAGE(Sp, (t + 1) * 64);
    #pragma unroll
    for (int m = 0; m < 4; ++m)
      #pragma unroll
      for (int n = 0; n < 4; ++n)
        acc[m][n] = __builtin_amdgcn_mfma_f32_16x16x32_bf16(a[m], b[n], acc[m][n], 0, 0, 0);
    // ---- sub 2: kk1 ----
    #pragma unroll
    for (int m = 0; m < 4; ++m) a[m] = *(const short8*)(Bp + (rdA^64) + m*2048);
    #pragma unroll
    for (int n = 0; n < 4; ++n) b[n] = *(const short8*)(Bp + 32768 + (rdB^64) + n*2048);
    #pragma unroll
    for (int m = 0; m < 4; ++m)
      #pragma unroll
      for (int n = 0; n < 4; ++n)
        acc[m][n] = __builtin_amdgcn_mfma_f32_16x16x32_bf16(a[m], b[n], acc[m][n], 0, 0, 0);
    WAIT_VM0();
    BAR();
    char* tmp = (char*)Bp; Bp = Sp; Sp = tmp;
  }
  #pragma unroll
  for (int m = 0; m < 4; ++m) {
    int trb = wm*64 + m*16 + kg*4;
    #pragma unroll
    for (int n = 0; n < 4; ++n) {
      int col = n0b + wn*64 + n*16 + r16;
      #pragma unroll
      for (int j = 0; j < 4; ++j) {
        int tr = trb + j;
        if (mbase + tr < mend) {
          float val = acc[m][n][j];
          if (SH) {
            out[(size_t)(mbase + tr) * DIM + col] = val;
          } else {
            int tok = entry[arow0 + tr];
            float gv = wgt[arow0 + tr];
            atomicAdd(&out[(size_t)tok * DIM + col], val * gv);
          }
        }
      }
    }
  }
}

extern "C" void kernel_launch(void* const* d_in, const int* in_sizes, int n_in,
                              void* d_out, int out_size, void* d_ws, size_t ws_size,
                              hipStream_t stream)
{
  const float* x   = (const float*)d_in[0];
  const float* gw  = (const float*)d_in[1];
  const float* ew1 = (const float*)d_in[2];
  const float* ew2 = (const float*)d_in[3];
  const float* ew3 = (const float*)d_in[4];
  const float* sw1 = (const float*)d_in[5];
  const float* sw2 = (const float*)d_in[6];
  const float* sw3 = (const float*)d_in[7];
  float* out = (float*)d_out;
  char* ws = (char*)d_ws;

  int*   counts = (int*)ws;
  int*   offs   = counts + 8;
  int*   fill   = offs + 9;
  int*   topi   = fill + 8;
  float* topw   = (float*)(topi + 2*NTOK);
  int*   entry  = (int*)(topw + 2*NTOK);
  float* wgt    = (float*)(entry + 2*NTOK);
  unsigned short* xb  = (unsigned short*)(ws + (1u<<20));
  unsigned short* act = (unsigned short*)(ws + (1u<<20) + (16u<<20));
  unsigned short* wt  = (unsigned short*)(ws + (1u<<20) + (16u<<20) + (96u<<20));

  hipMemsetAsync(counts, 0, 8*sizeof(int), stream);
  k_gate<<<NTOK/4, 256, 0, stream>>>(x, gw, topi, topw, counts);
  k_scan<<<1, 64, 0, stream>>>(counts, offs, fill);
  k_scatter<<<NTOK/256, 256, 0, stream>>>(topi, topw, fill, entry, wgt);
  k_castx<<<(NTOK*DIM/4)/256, 256, 0, stream>>>(x, xb);
  k_tr<<<dim3(32, 32, 27), 256, 0, stream>>>(ew1, ew2, ew3, sw1, sw2, sw3, wt);
  k_up<<<dim3(16, 288), 512, 0, stream>>>(xb, wt, offs, entry, act);
  k_down<true><<<dim3(8, 32), 512, 0, stream>>>(act, wt, offs, entry, wgt, out);
  k_down<false><<<dim3(8, 256), 512, 0, stream>>>(act, wt, offs, entry, wgt, out);
}